// Round 9
// baseline (2527.730 us; speedup 1.0000x reference)
//
#include <hip/hip_runtime.h>
#include <hip/hip_bf16.h>
#include <math.h>

#define BB 8
#define NN 2048
#define KK 10
#define BN (BB * NN)

#define TR 64
#define TC 64
#define TF 32
#define SPLIT 4
#define CPS (NN / SPLIT)   // 512 cols per split-block (fp32 layer-0 path)
#define NSPL 8             // col-split for MFMA knn (256 cols/block)

typedef __attribute__((ext_vector_type(8))) short bf16x8;
typedef __attribute__((ext_vector_type(4))) float f32x4;

__device__ inline unsigned short f2bf(float f) {
    unsigned int u = __float_as_uint(f);
    unsigned int r = u + 0x7fffu + ((u >> 16) & 1u);
    return (unsigned short)(r >> 16);
}
__device__ inline float bf2f(unsigned short h) {
    return __uint_as_float((unsigned int)h << 16);
}

// ---------------------------------------------------------------------------
// sq[i] = sum_f x[i,f]^2
__global__ void sqnorm_kernel(const float* __restrict__ x, float* __restrict__ sq, int F) {
    int i = blockIdx.x * blockDim.x + threadIdx.x;
    if (i >= BN) return;
    const float* xp = x + (size_t)i * F;
    float s = 0.f;
    for (int f = 0; f < F; ++f) { float v = xp[f]; s += v * v; }
    sq[i] = s;
}

// ---------------------------------------------------------------------------
// kNN fp32 path (layer 0, F=3 only) — validated round 3
__global__ __launch_bounds__(256, 4) void knn_part_kernel(const float* __restrict__ x,
                                                          const float* __restrict__ sq,
                                                          float* __restrict__ candD,
                                                          int* __restrict__ candI, int F) {
    int b = blockIdx.z;
    int row0 = blockIdx.x * TR;
    int colbase = blockIdx.y * CPS;
    const float* xb = x + (size_t)b * NN * F;
    const float* sqb = sq + (size_t)b * NN;

    __shared__ float smem[TF * 68 * 2 + TR * 65];
    float* As = smem;
    float* Bs = smem + TF * 68;
    float* Ds = smem + TF * 68 * 2;

    int tid = threadIdx.x;
    int tr = (tid / 16) * 4;
    int tc = (tid % 16) * 4;
    int srow = tid & 63;
    int squart = tid >> 6;
    int scol0 = squart * 16;

    float bestd[KK];
    int bestidx[KK];
#pragma unroll
    for (int k = 0; k < KK; ++k) { bestd[k] = INFINITY; bestidx[k] = 0x7fffffff; }

    for (int ct = 0; ct < CPS; ct += TC) {
        int col0 = colbase + ct;
        float acc[4][4];
#pragma unroll
        for (int i = 0; i < 4; ++i)
#pragma unroll
            for (int j = 0; j < 4; ++j) acc[i][j] = 0.f;

        for (int f0 = 0; f0 < F; f0 += TF) {
            __syncthreads();
            for (int l = tid; l < TR * TF; l += 256) {
                int r = l / TF, f = l % TF;
                As[f * 68 + r] = (f0 + f < F) ? xb[(size_t)(row0 + r) * F + f0 + f] : 0.f;
                Bs[f * 68 + r] = (f0 + f < F) ? xb[(size_t)(col0 + r) * F + f0 + f] : 0.f;
            }
            __syncthreads();
#pragma unroll
            for (int f = 0; f < TF; ++f) {
                float a[4], bv[4];
#pragma unroll
                for (int i = 0; i < 4; ++i) a[i] = As[f * 68 + tr + i];
#pragma unroll
                for (int j = 0; j < 4; ++j) bv[j] = Bs[f * 68 + tc + j];
#pragma unroll
                for (int i = 0; i < 4; ++i)
#pragma unroll
                    for (int j = 0; j < 4; ++j) acc[i][j] += a[i] * bv[j];
            }
        }
        __syncthreads();
#pragma unroll
        for (int i = 0; i < 4; ++i) {
            float sr = sqb[row0 + tr + i];
#pragma unroll
            for (int j = 0; j < 4; ++j) {
                Ds[(tr + i) * 65 + tc + j] = (sr + sqb[col0 + tc + j]) - 2.f * acc[i][j];
            }
        }
        __syncthreads();
#pragma unroll
        for (int cc = 0; cc < 16; ++cc) {
            int c = scol0 + cc;
            float d = Ds[srow * 65 + c];
            if (d < bestd[KK - 1]) {
                bestd[KK - 1] = d;
                bestidx[KK - 1] = col0 + c;
#pragma unroll
                for (int p = KK - 1; p > 0; --p) {
                    if (bestd[p] < bestd[p - 1]) {
                        float td = bestd[p]; bestd[p] = bestd[p - 1]; bestd[p - 1] = td;
                        int ti = bestidx[p]; bestidx[p] = bestidx[p - 1]; bestidx[p - 1] = ti;
                    }
                }
            }
        }
    }
    __syncthreads();
    float* candd_s = smem;
    int* candi_s = (int*)(smem + 256 * KK);
#pragma unroll
    for (int k = 0; k < KK; ++k) {
        candd_s[tid * KK + k] = bestd[k];
        candi_s[tid * KK + k] = bestidx[k];
    }
    __syncthreads();
    if (tid < TR) {
        int p[4] = {0, 0, 0, 0};
        size_t base = ((size_t)((size_t)b * NN + row0 + tid) * SPLIT + blockIdx.y) * KK;
        for (int s = 0; s < KK; ++s) {
            float bD = INFINITY; int bI = 0x7fffffff; int bq = 0;
#pragma unroll
            for (int q = 0; q < 4; ++q) {
                if (p[q] < KK) {
                    int li = (q * 64 + tid) * KK + p[q];
                    float d = candd_s[li]; int ii = candi_s[li];
                    if (d < bD || (d == bD && ii < bI)) { bD = d; bI = ii; bq = q; }
                }
            }
            p[bq]++;
            candD[base + s] = bD;
            candI[base + s] = bI;
        }
    }
}

// ---------------------------------------------------------------------------
// kNN MFMA path (layers 1-4), round 9 restructure:
//  - A fragments loaded DIRECTLY from global (rows fixed per thread; aligned
//    16B loads, L2-resident across ct reuse) — A out of the barrier path.
//  - B staged through a DOUBLE-BUFFERED LDS pair (2 x (Bh|Bl) = 40 KB exactly):
//    stage chunk k+1 while computing chunk k -> 1 barrier per chunk.
//  - Ds (64x133) + merge arrays overlaid on the same 40 KB pool.
//  - NSPL=8 -> 1024 blocks (~4/CU avg, 3 resident) for cross-block overlap.
__global__ __launch_bounds__(256, 3) void knn_mfma_kernel(
        const unsigned short* __restrict__ xh, const unsigned short* __restrict__ xl,
        const float* __restrict__ sq, float* __restrict__ candD,
        int* __restrict__ candI, int F) {
    int b = blockIdx.z;
    int row0 = blockIdx.x * 128;
    int colbase = blockIdx.y * (NN / NSPL);   // 256 cols per block
    const unsigned short* xhb = xh + (size_t)b * NN * F;
    const unsigned short* xlb = xl + (size_t)b * NN * F;
    const float* sqb = sq + (size_t)b * NN;

    __shared__ __align__(16) unsigned char smem_raw[40960];   // 40 KB pool
    unsigned short* Bbuf0 = (unsigned short*)smem_raw;        // [Bh|Bl] 2*5120
    unsigned short* Bbuf1 = Bbuf0 + 2 * 128 * 40;             // second buffer
    float* DsS = (float*)smem_raw;                            // overlay [64*133]
    float* cd = (float*)smem_raw;                             // overlay merge
    int* ci = (int*)smem_raw + 2560;

    int tid = threadIdx.x;
    int lane = tid & 63;
    int wave = tid >> 6;
    int wr = (wave >> 1) * 64, wc = (wave & 1) * 64;
    int l15 = lane & 15, kq = lane >> 4;
    int whalf = wave >> 1;
    int srow = tid & 63;
    int scol0 = (tid >> 6) * 32;

    float sqr[4][4];
#pragma unroll
    for (int mt = 0; mt < 4; ++mt)
#pragma unroll
        for (int r = 0; r < 4; ++r)
            sqr[mt][r] = sqb[row0 + wr + mt * 16 + kq * 4 + r];

    float bestd[2][KK];
    int besti[2][KK];
#pragma unroll
    for (int h = 0; h < 2; ++h)
#pragma unroll
        for (int k = 0; k < KK; ++k) { bestd[h][k] = INFINITY; besti[h][k] = 0x7fffffff; }

    int nk = F >> 5;   // K-chunks of 32

    for (int ct = 0; ct < (NN / NSPL) / 128; ++ct) {   // 2 col-tiles of 128
        int col0 = colbase + ct * 128;
        f32x4 acc[4][4];
#pragma unroll
        for (int mt = 0; mt < 4; ++mt)
#pragma unroll
            for (int nt = 0; nt < 4; ++nt) acc[mt][nt] = (f32x4){0.f, 0.f, 0.f, 0.f};

        __syncthreads();   // prior selection/merge scans done before staging overlay
        // stage chunk 0 into Bbuf0: 1024 uint4 (Bh 512 + Bl 512), 4/thread
#pragma unroll
        for (int it = 0; it < 4; ++it) {
            int i = tid + it * 256;
            int rs = i & 511;
            int row = rs >> 2, sub = rs & 3;
            const unsigned short* src = ((i >> 9) ? xlb : xhb) + (size_t)(col0 + row) * F + sub * 8;
            unsigned short* dst = Bbuf0 + (i >> 9) * (128 * 40) + row * 40 + sub * 8;
            *(uint4*)dst = *(const uint4*)src;
        }

        unsigned short* bufs[2] = {Bbuf0, Bbuf1};
        int cur = 0;
        for (int kci = 0; kci < nk; ++kci) {
            int kc = kci * 32;
            __syncthreads();   // buf[cur] staged; prior reads of buf[cur] done
            if (kci + 1 < nk) {
                unsigned short* nb = bufs[cur ^ 1];
                int kc2 = kc + 32;
#pragma unroll
                for (int it = 0; it < 4; ++it) {
                    int i = tid + it * 256;
                    int rs = i & 511;
                    int row = rs >> 2, sub = rs & 3;
                    const unsigned short* src = ((i >> 9) ? xlb : xhb) + (size_t)(col0 + row) * F + kc2 + sub * 8;
                    unsigned short* dst = nb + (i >> 9) * (128 * 40) + row * 40 + sub * 8;
                    *(uint4*)dst = *(const uint4*)src;
                }
            }
            unsigned short* Bh = bufs[cur];
            unsigned short* Bl = Bh + 128 * 40;
            bf16x8 bh[4], bl[4];
#pragma unroll
            for (int t = 0; t < 4; ++t) {
                bh[t] = *(const bf16x8*)&Bh[(wc + t * 16 + l15) * 40 + kq * 8];
                bl[t] = *(const bf16x8*)&Bl[(wc + t * 16 + l15) * 40 + kq * 8];
            }
#pragma unroll
            for (int mt = 0; mt < 4; ++mt) {
                size_t roff = (size_t)(row0 + wr + mt * 16 + l15) * F + kc + kq * 8;
                bf16x8 ah = *(const bf16x8*)&xhb[roff];
                bf16x8 al = *(const bf16x8*)&xlb[roff];
#pragma unroll
                for (int nt = 0; nt < 4; ++nt) {
                    acc[mt][nt] = __builtin_amdgcn_mfma_f32_16x16x32_bf16(ah, bh[nt], acc[mt][nt], 0, 0, 0);
                    acc[mt][nt] = __builtin_amdgcn_mfma_f32_16x16x32_bf16(al, bh[nt], acc[mt][nt], 0, 0, 0);
                    acc[mt][nt] = __builtin_amdgcn_mfma_f32_16x16x32_bf16(ah, bl[nt], acc[mt][nt], 0, 0, 0);
                }
            }
            cur ^= 1;
        }
        float sqc[4];
#pragma unroll
        for (int nt = 0; nt < 4; ++nt) sqc[nt] = sqb[col0 + wc + nt * 16 + l15];

        __syncthreads();   // all frag reads done before Ds overlay write
#pragma unroll
        for (int h = 0; h < 2; ++h) {
            if (whalf == h) {
#pragma unroll
                for (int mt = 0; mt < 4; ++mt)
#pragma unroll
                    for (int nt = 0; nt < 4; ++nt)
#pragma unroll
                        for (int r = 0; r < 4; ++r)
                            DsS[(mt * 16 + kq * 4 + r) * 133 + wc + nt * 16 + l15] =
                                (sqr[mt][r] + sqc[nt]) - 2.f * acc[mt][nt][r];
            }
            __syncthreads();
#pragma unroll
            for (int cc = 0; cc < 32; ++cc) {
                int c = scol0 + cc;
                float d = DsS[srow * 133 + c];
                if (d < bestd[h][KK - 1]) {
                    bestd[h][KK - 1] = d;
                    besti[h][KK - 1] = col0 + c;
#pragma unroll
                    for (int p = KK - 1; p > 0; --p) {
                        if (bestd[h][p] < bestd[h][p - 1]) {
                            float td = bestd[h][p]; bestd[h][p] = bestd[h][p - 1]; bestd[h][p - 1] = td;
                            int ti = besti[h][p]; besti[h][p] = besti[h][p - 1]; besti[h][p - 1] = ti;
                        }
                    }
                }
            }
            __syncthreads();   // scan done before next half's write / next ct stage
        }
    }
    // in-block 4-way merge per row, per half
#pragma unroll
    for (int h = 0; h < 2; ++h) {
        __syncthreads();
#pragma unroll
        for (int k = 0; k < KK; ++k) {
            cd[tid * KK + k] = bestd[h][k];
            ci[tid * KK + k] = besti[h][k];
        }
        __syncthreads();
        if (tid < 64) {
            int p[4] = {0, 0, 0, 0};
            size_t base = ((size_t)((size_t)b * NN + row0 + h * 64 + tid) * NSPL + blockIdx.y) * KK;
            for (int s = 0; s < KK; ++s) {
                float bD = INFINITY; int bI = 0x7fffffff; int bq = 0;
#pragma unroll
                for (int q = 0; q < 4; ++q) {
                    if (p[q] < KK) {
                        int li = (q * 64 + tid) * KK + p[q];
                        float d = cd[li]; int ii = ci[li];
                        if (d < bD || (d == bD && ii < bI)) { bD = d; bI = ii; bq = q; }
                    }
                }
                p[bq]++;
                candD[base + s] = bD;
                candI[base + s] = bI;
            }
        }
    }
}

// ---------------------------------------------------------------------------
// merge nsplit (<=8) sorted 10-lists per row -> final top-10 indices
__global__ void knn_merge_kernel(const float* __restrict__ candD,
                                 const int* __restrict__ candI,
                                 int* __restrict__ idx, int nsplit) {
    int g = blockIdx.x * blockDim.x + threadIdx.x;
    if (g >= BN) return;
    size_t base = (size_t)g * nsplit * KK;
    int p[8] = {0, 0, 0, 0, 0, 0, 0, 0};
    int* op = idx + (size_t)g * KK;
    for (int s = 0; s < KK; ++s) {
        float bD = INFINITY; int bI = 0x7fffffff; int bq = 0;
        for (int q = 0; q < nsplit; ++q) {
            if (p[q] < KK) {
                float d = candD[base + q * KK + p[q]];
                int ii = candI[base + q * KK + p[q]];
                if (d < bD || (d == bD && ii < bI)) { bD = d; bI = ii; bq = q; }
            }
        }
        p[bq]++;
        op[s] = bI;
    }
}

// ---------------------------------------------------------------------------
// split x (fp32) into hi/lo bf16
__global__ void xsplit_kernel(const float* __restrict__ x, unsigned short* __restrict__ hi,
                              unsigned short* __restrict__ lo, int n) {
    int i = blockIdx.x * blockDim.x + threadIdx.x;
    if (i >= n) return;
    float v = x[i];
    unsigned short h = f2bf(v);
    hi[i] = h;
    lo[i] = f2bf(v - bf2f(h));
}

// ---------------------------------------------------------------------------
// Build WT[o'][2*fin] bf16: rows o'<fout -> (W1-W2) col o', else W2 col o'-fout.
__global__ void wsplit_kernel(const float* __restrict__ w, unsigned short* __restrict__ WT,
                              int fin, int fout) {
    int i = blockIdx.x * blockDim.x + threadIdx.x;
    int total = 2 * fout * fin;
    if (i >= total) return;
    int op = i % (2 * fout);
    int f = i / (2 * fout);
    float v;
    if (op < fout) v = w[(size_t)f * fout + op] - w[(size_t)(fin + f) * fout + op];
    else v = w[(size_t)(fin + f) * fout + (op - fout)];
    unsigned short h = f2bf(v);
    unsigned short l = f2bf(v - bf2f(h));
    WT[(size_t)op * (2 * fin) + f] = h;
    WT[(size_t)op * (2 * fin) + fin + f] = l;
}

// ---------------------------------------------------------------------------
// MFMA GEMM (validated round 5): A|T = xsplit @ WT^T, 3-phase bf16 split.
__global__ __launch_bounds__(256) void gemm2_mfma_kernel(
        const unsigned short* __restrict__ XSh, const unsigned short* __restrict__ XSl,
        const unsigned short* __restrict__ WT, const float* __restrict__ bias,
        float* __restrict__ Aout, float* __restrict__ Tout, int fin, int fout) {
    int m0 = blockIdx.x * 128;
    int n0 = blockIdx.y * 128;
    __shared__ __align__(16) unsigned short As[128 * 40];
    __shared__ __align__(16) unsigned short Bs[128 * 40];
    int tid = threadIdx.x;
    int lane = tid & 63;
    int wave = tid >> 6;
    int wr = (wave >> 1) * 64, wc = (wave & 1) * 64;
    int l15 = lane & 15, kq = lane >> 4;
    int w2f = 2 * fin;

    f32x4 acc[4][4];
#pragma unroll
    for (int mt = 0; mt < 4; ++mt)
#pragma unroll
        for (int nt = 0; nt < 4; ++nt) acc[mt][nt] = (f32x4){0.f, 0.f, 0.f, 0.f};

    for (int p = 0; p < 3; ++p) {
        const unsigned short* Axp = (p == 1) ? XSl : XSh;
        int bkoff = (p == 2) ? fin : 0;
        for (int kc = 0; kc < fin; kc += 32) {
            __syncthreads();
            for (int i = tid; i < 512; i += 256) {
                int row = i >> 2, sub = i & 3;
                *(uint4*)&As[row * 40 + sub * 8] =
                    *(const uint4*)&Axp[(size_t)(m0 + row) * fin + kc + sub * 8];
                *(uint4*)&Bs[row * 40 + sub * 8] =
                    *(const uint4*)&WT[(size_t)(n0 + row) * w2f + bkoff + kc + sub * 8];
            }
            __syncthreads();
            bf16x8 a[4], b[4];
#pragma unroll
            for (int t = 0; t < 4; ++t) {
                a[t] = *(const bf16x8*)&As[(wr + t * 16 + l15) * 40 + kq * 8];
                b[t] = *(const bf16x8*)&Bs[(wc + t * 16 + l15) * 40 + kq * 8];
            }
#pragma unroll
            for (int mt = 0; mt < 4; ++mt)
#pragma unroll
                for (int nt = 0; nt < 4; ++nt)
                    acc[mt][nt] = __builtin_amdgcn_mfma_f32_16x16x32_bf16(a[mt], b[nt], acc[mt][nt], 0, 0, 0);
        }
    }
#pragma unroll
    for (int mt = 0; mt < 4; ++mt) {
        int mbase = m0 + wr + mt * 16 + kq * 4;
#pragma unroll
        for (int nt = 0; nt < 4; ++nt) {
            int oc = n0 + wc + nt * 16 + l15;
            f32x4 c = acc[mt][nt];
            if (oc < fout) {
                float bv = bias[oc];
#pragma unroll
                for (int r = 0; r < 4; ++r)
                    Aout[(size_t)(mbase + r) * fout + oc] = c[r] + bv;
            } else {
                int o2 = oc - fout;
#pragma unroll
                for (int r = 0; r < 4; ++r)
                    Tout[(size_t)(mbase + r) * fout + o2] = c[r];
            }
        }
    }
}

// ---------------------------------------------------------------------------
// fp32 gemm2 (layer 0, fin=3)
__global__ __launch_bounds__(256) void gemm2_kernel(const float* __restrict__ x,
                                                    const float* __restrict__ w,
                                                    const float* __restrict__ bias,
                                                    float* __restrict__ Aout,
                                                    float* __restrict__ Tout,
                                                    int fin, int fout) {
    int m0 = blockIdx.x * 64;
    int o0 = blockIdx.y * 64;
    __shared__ float Xs[64][TF + 1];
    __shared__ float W1s[TF][64];
    __shared__ float W2s[TF][64];
    int tid = threadIdx.x;
    int tr = (tid / 16) * 4, tc = (tid % 16) * 4;
    float accA[4][4], accT[4][4];
#pragma unroll
    for (int i = 0; i < 4; ++i)
#pragma unroll
        for (int j = 0; j < 4; ++j) { accA[i][j] = 0.f; accT[i][j] = 0.f; }

    for (int f0 = 0; f0 < fin; f0 += TF) {
        __syncthreads();
        for (int l = tid; l < 64 * TF; l += 256) {
            int r = l / TF, f = l % TF;
            Xs[r][f] = (f0 + f < fin) ? x[(size_t)(m0 + r) * fin + f0 + f] : 0.f;
        }
        for (int l = tid; l < TF * 64; l += 256) {
            int f = l / 64, o = l % 64;
            bool ok = (f0 + f < fin);
            W1s[f][o] = ok ? w[(size_t)(f0 + f) * fout + o0 + o] : 0.f;
            W2s[f][o] = ok ? w[(size_t)(f0 + f + fin) * fout + o0 + o] : 0.f;
        }
        __syncthreads();
#pragma unroll
        for (int f = 0; f < TF; ++f) {
            float a[4], w1[4], w2[4];
#pragma unroll
            for (int i = 0; i < 4; ++i) a[i] = Xs[tr + i][f];
#pragma unroll
            for (int j = 0; j < 4; ++j) { w1[j] = W1s[f][tc + j]; w2[j] = W2s[f][tc + j]; }
#pragma unroll
            for (int i = 0; i < 4; ++i)
#pragma unroll
                for (int j = 0; j < 4; ++j) {
                    accA[i][j] += a[i] * (w1[j] - w2[j]);
                    accT[i][j] += a[i] * w2[j];
                }
        }
    }
#pragma unroll
    for (int i = 0; i < 4; ++i)
#pragma unroll
        for (int j = 0; j < 4; ++j) {
            int m = m0 + tr + i, o = o0 + tc + j;
            Aout[(size_t)m * fout + o] = accA[i][j] + bias[o];
            Tout[(size_t)m * fout + o] = accT[i][j];
        }
}

// ---------------------------------------------------------------------------
__global__ void gathermax_kernel(const float* __restrict__ A, const float* __restrict__ T,
                                 const int* __restrict__ idx, float* __restrict__ out,
                                 int fout) {
    int pn = blockIdx.x;
    int b = pn / NN;
    int o = blockIdx.y * 64 + threadIdx.x;
    const int* ip = idx + (size_t)pn * KK;
    const float* Tb = T + (size_t)b * NN * fout;
    float m = -INFINITY;
#pragma unroll
    for (int k = 0; k < KK; ++k) {
        int j = ip[k];
        m = fmaxf(m, Tb[(size_t)j * fout + o]);
    }
    float h = A[(size_t)pn * fout + o] + m;
    out[(size_t)pn * fout + o] = h > 0.f ? h : 0.2f * h;
}

// ---------------------------------------------------------------------------
__global__ void gmax_kernel(const float* __restrict__ h, float* __restrict__ g) {
    int b = blockIdx.y;
    int o = blockIdx.x * 256 + threadIdx.x;
    const float* hp = h + (size_t)b * NN * 1024 + o;
    float m = -INFINITY;
    for (int n = 0; n < NN; ++n) m = fmaxf(m, hp[(size_t)n * 1024]);
    g[(size_t)b * 1024 + o] = m;
}

// ---------------------------------------------------------------------------
__global__ __launch_bounds__(128) void mlp_kernel(const float* __restrict__ g,
                                                  const float* __restrict__ m0w, const float* __restrict__ m0b,
                                                  const float* __restrict__ m1w, const float* __restrict__ m1b,
                                                  const float* __restrict__ m2w, const float* __restrict__ m2b,
                                                  float* __restrict__ out) {
    __shared__ float gs[1024];
    __shared__ float h1[128];
    __shared__ float h2[64];
    int b = blockIdx.x, t = threadIdx.x;
    for (int i = t; i < 1024; i += 128) gs[i] = g[(size_t)b * 1024 + i];
    __syncthreads();
    float s = m0b[t];
    for (int f = 0; f < 1024; ++f) s += gs[f] * m0w[(size_t)f * 128 + t];
    h1[t] = s;
    __syncthreads();
    if (t < 64) {
        float s2 = m1b[t];
        for (int f = 0; f < 128; ++f) s2 += h1[f] * m1w[(size_t)f * 64 + t];
        h2[t] = s2;
    }
    __syncthreads();
    if (t == 0) {
        float s3 = m2b[0];
        for (int f = 0; f < 64; ++f) s3 += h2[f] * m2w[f];
        out[b] = s3;
    }
}

// ---------------------------------------------------------------------------
extern "C" void kernel_launch(void* const* d_in, const int* in_sizes, int n_in,
                              void* d_out, int out_size, void* d_ws, size_t ws_size,
                              hipStream_t stream) {
    const float* x0 = (const float*)d_in[0];
    const float* w[5], * bi[5];
    for (int i = 0; i < 5; ++i) { w[i] = (const float*)d_in[1 + 2 * i]; bi[i] = (const float*)d_in[2 + 2 * i]; }
    const float* m0w = (const float*)d_in[11]; const float* m0b = (const float*)d_in[12];
    const float* m1w = (const float*)d_in[13]; const float* m1b = (const float*)d_in[14];
    const float* m2w = (const float*)d_in[15]; const float* m2b = (const float*)d_in[16];

    float* X0 = (float*)d_ws;
    float* X1 = X0 + (size_t)BN * 1024;
    float* T  = X1 + (size_t)BN * 1024;
    float* SQ = T  + (size_t)BN * 1024;
    int*   IDX = (int*)(SQ + BN);
    float* G  = (float*)(IDX + (size_t)BN * KK);
    unsigned short* XSh = (unsigned short*)(G + (size_t)BB * 1024);
    unsigned short* XSl = XSh + (size_t)BN * 512;   // max fin = 512
    unsigned short* WT  = XSl + (size_t)BN * 512;   // max 2*1024 x 2*512 bf16

    // candidate buffers overlaid on T region (T written only after kNN done)
    float* candD = T;
    int*   candI = (int*)(T + (size_t)BN * NSPL * KK);

    const int fouts[5] = {64, 128, 256, 512, 1024};
    const float* cur = x0;
    int fin = 3;
    float* bufs[2] = {X0, X1};

    for (int l = 0; l < 5; ++l) {
        int fout = fouts[l];
        float* nxt = bufs[l & 1];

        sqnorm_kernel<<<(BN + 255) / 256, 256, 0, stream>>>(cur, SQ, fin);

        if (l == 0) {
            dim3 kg(NN / TR, SPLIT, BB);
            knn_part_kernel<<<kg, 256, 0, stream>>>(cur, SQ, candD, candI, fin);
            knn_merge_kernel<<<(BN + 255) / 256, 256, 0, stream>>>(candD, candI, IDX, SPLIT);

            dim3 gg(BN / 64, fout / 64);
            gemm2_kernel<<<gg, 256, 0, stream>>>(cur, w[l], bi[l], nxt, T, fin, fout);
        } else {
            int nx = BN * fin;
            xsplit_kernel<<<(nx + 255) / 256, 256, 0, stream>>>(cur, XSh, XSl, nx);

            dim3 kg(NN / 128, NSPL, BB);
            knn_mfma_kernel<<<kg, 256, 0, stream>>>(XSh, XSl, SQ, candD, candI, fin);
            knn_merge_kernel<<<(BN + 255) / 256, 256, 0, stream>>>(candD, candI, IDX, NSPL);

            int nw = 2 * fout * fin;
            wsplit_kernel<<<(nw + 255) / 256, 256, 0, stream>>>(w[l], WT, fin, fout);
            dim3 gg(BN / 128, (2 * fout) / 128);
            gemm2_mfma_kernel<<<gg, 256, 0, stream>>>(XSh, XSl, WT, bi[l], nxt, T, fin, fout);
        }

        dim3 mg(BN, fout / 64);
        gathermax_kernel<<<mg, 64, 0, stream>>>(nxt, T, IDX, nxt, fout);

        cur = nxt;
        fin = fout;
    }

    dim3 xg(1024 / 256, BB);
    gmax_kernel<<<xg, 256, 0, stream>>>(cur, G);

    mlp_kernel<<<BB, 128, 0, stream>>>(G, m0w, m0b, m1w, m1b, m2w, m2b, (float*)d_out);
}

// Round 10
// 2393.798 us; speedup vs baseline: 1.0559x; 1.0559x over previous
//
#include <hip/hip_runtime.h>
#include <hip/hip_bf16.h>
#include <math.h>

#define BB 8
#define NN 2048
#define KK 10
#define BN (BB * NN)

#define TR 64
#define TC 64
#define TF 32
#define SPLIT 4
#define CPS (NN / SPLIT)   // 512 cols per split-block (fp32 layer-0 path)
#define QC 512             // cols per d2 quarter-pass (MFMA knn)

typedef __attribute__((ext_vector_type(8))) short bf16x8;
typedef __attribute__((ext_vector_type(4))) float f32x4;

__device__ inline unsigned short f2bf(float f) {
    unsigned int u = __float_as_uint(f);
    unsigned int r = u + 0x7fffu + ((u >> 16) & 1u);
    return (unsigned short)(r >> 16);
}
__device__ inline float bf2f(unsigned short h) {
    return __uint_as_float((unsigned int)h << 16);
}

// ---------------------------------------------------------------------------
// sq[i] = sum_f x[i,f]^2
__global__ void sqnorm_kernel(const float* __restrict__ x, float* __restrict__ sq, int F) {
    int i = blockIdx.x * blockDim.x + threadIdx.x;
    if (i >= BN) return;
    const float* xp = x + (size_t)i * F;
    float s = 0.f;
    for (int f = 0; f < F; ++f) { float v = xp[f]; s += v * v; }
    sq[i] = s;
}

// ---------------------------------------------------------------------------
// kNN fp32 path (layer 0, F=3 only) — validated round 3
__global__ __launch_bounds__(256, 4) void knn_part_kernel(const float* __restrict__ x,
                                                          const float* __restrict__ sq,
                                                          float* __restrict__ candD,
                                                          int* __restrict__ candI, int F) {
    int b = blockIdx.z;
    int row0 = blockIdx.x * TR;
    int colbase = blockIdx.y * CPS;
    const float* xb = x + (size_t)b * NN * F;
    const float* sqb = sq + (size_t)b * NN;

    __shared__ float smem[TF * 68 * 2 + TR * 65];
    float* As = smem;
    float* Bs = smem + TF * 68;
    float* Ds = smem + TF * 68 * 2;

    int tid = threadIdx.x;
    int tr = (tid / 16) * 4;
    int tc = (tid % 16) * 4;
    int srow = tid & 63;
    int squart = tid >> 6;
    int scol0 = squart * 16;

    float bestd[KK];
    int bestidx[KK];
#pragma unroll
    for (int k = 0; k < KK; ++k) { bestd[k] = INFINITY; bestidx[k] = 0x7fffffff; }

    for (int ct = 0; ct < CPS; ct += TC) {
        int col0 = colbase + ct;
        float acc[4][4];
#pragma unroll
        for (int i = 0; i < 4; ++i)
#pragma unroll
            for (int j = 0; j < 4; ++j) acc[i][j] = 0.f;

        for (int f0 = 0; f0 < F; f0 += TF) {
            __syncthreads();
            for (int l = tid; l < TR * TF; l += 256) {
                int r = l / TF, f = l % TF;
                As[f * 68 + r] = (f0 + f < F) ? xb[(size_t)(row0 + r) * F + f0 + f] : 0.f;
                Bs[f * 68 + r] = (f0 + f < F) ? xb[(size_t)(col0 + r) * F + f0 + f] : 0.f;
            }
            __syncthreads();
#pragma unroll
            for (int f = 0; f < TF; ++f) {
                float a[4], bv[4];
#pragma unroll
                for (int i = 0; i < 4; ++i) a[i] = As[f * 68 + tr + i];
#pragma unroll
                for (int j = 0; j < 4; ++j) bv[j] = Bs[f * 68 + tc + j];
#pragma unroll
                for (int i = 0; i < 4; ++i)
#pragma unroll
                    for (int j = 0; j < 4; ++j) acc[i][j] += a[i] * bv[j];
            }
        }
        __syncthreads();
#pragma unroll
        for (int i = 0; i < 4; ++i) {
            float sr = sqb[row0 + tr + i];
#pragma unroll
            for (int j = 0; j < 4; ++j) {
                Ds[(tr + i) * 65 + tc + j] = (sr + sqb[col0 + tc + j]) - 2.f * acc[i][j];
            }
        }
        __syncthreads();
#pragma unroll
        for (int cc = 0; cc < 16; ++cc) {
            int c = scol0 + cc;
            float d = Ds[srow * 65 + c];
            if (d < bestd[KK - 1]) {
                bestd[KK - 1] = d;
                bestidx[KK - 1] = col0 + c;
#pragma unroll
                for (int p = KK - 1; p > 0; --p) {
                    if (bestd[p] < bestd[p - 1]) {
                        float td = bestd[p]; bestd[p] = bestd[p - 1]; bestd[p - 1] = td;
                        int ti = bestidx[p]; bestidx[p] = bestidx[p - 1]; bestidx[p - 1] = ti;
                    }
                }
            }
        }
    }
    __syncthreads();
    float* candd_s = smem;
    int* candi_s = (int*)(smem + 256 * KK);
#pragma unroll
    for (int k = 0; k < KK; ++k) {
        candd_s[tid * KK + k] = bestd[k];
        candi_s[tid * KK + k] = bestidx[k];
    }
    __syncthreads();
    if (tid < TR) {
        int p[4] = {0, 0, 0, 0};
        size_t base = ((size_t)((size_t)b * NN + row0 + tid) * SPLIT + blockIdx.y) * KK;
        for (int s = 0; s < KK; ++s) {
            float bD = INFINITY; int bI = 0x7fffffff; int bq = 0;
#pragma unroll
            for (int q = 0; q < 4; ++q) {
                if (p[q] < KK) {
                    int li = (q * 64 + tid) * KK + p[q];
                    float d = candd_s[li]; int ii = candi_s[li];
                    if (d < bD || (d == bD && ii < bI)) { bD = d; bI = ii; bq = q; }
                }
            }
            p[bq]++;
            candD[base + s] = bD;
            candI[base + s] = bI;
        }
    }
}

// ---------------------------------------------------------------------------
// kNN Gram GEMM (layers 1-4, round 10): PURE MFMA GEMM writing d2 tiles to
// global scratch (quarter of columns per pass). Round-8 proven staging:
// Ah/Al/Bh/Bl together (2048 uint4, 8/thread), 2 barriers/chunk, 48 MFMA.
// d2[(b*NN+row)*QC + lc] = sq_i + sq_j - 2*Gram.
__global__ __launch_bounds__(256) void knn_gram_kernel(
        const unsigned short* __restrict__ xh, const unsigned short* __restrict__ xl,
        const float* __restrict__ sq, float* __restrict__ d2, int F, int qbase) {
    int b = blockIdx.z;
    int row0 = blockIdx.x * 128;
    int col0 = qbase + blockIdx.y * 128;          // global col
    const unsigned short* xhb = xh + (size_t)b * NN * F;
    const unsigned short* xlb = xl + (size_t)b * NN * F;
    const float* sqb = sq + (size_t)b * NN;

    __shared__ __align__(16) unsigned short AsB[4 * 128 * 40];   // 40 KB
    unsigned short* Ah = AsB;
    unsigned short* Al = Ah + 128 * 40;
    unsigned short* Bh = Al + 128 * 40;
    unsigned short* Bl = Bh + 128 * 40;

    int tid = threadIdx.x;
    int lane = tid & 63;
    int wave = tid >> 6;
    int wr = (wave >> 1) * 64, wc = (wave & 1) * 64;
    int l15 = lane & 15, kq = lane >> 4;

    f32x4 acc[4][4];
#pragma unroll
    for (int mt = 0; mt < 4; ++mt)
#pragma unroll
        for (int nt = 0; nt < 4; ++nt) acc[mt][nt] = (f32x4){0.f, 0.f, 0.f, 0.f};

    for (int kc = 0; kc < F; kc += 32) {
        __syncthreads();
#pragma unroll
        for (int it = 0; it < 8; ++it) {
            int i = tid + it * 256;            // 0..2047
            int tile = i >> 9;                 // 512 uint4 per tile
            int rs = i & 511;
            int row = rs >> 2, sub = rs & 3;
            const unsigned short* src;
            unsigned short* dst;
            if (tile == 0)      { src = xhb + (size_t)(row0 + row) * F; dst = Ah; }
            else if (tile == 1) { src = xlb + (size_t)(row0 + row) * F; dst = Al; }
            else if (tile == 2) { src = xhb + (size_t)(col0 + row) * F; dst = Bh; }
            else                { src = xlb + (size_t)(col0 + row) * F; dst = Bl; }
            *(uint4*)&dst[row * 40 + sub * 8] = *(const uint4*)&src[kc + sub * 8];
        }
        __syncthreads();
        bf16x8 bh[4], bl[4];
#pragma unroll
        for (int t = 0; t < 4; ++t) {
            bh[t] = *(const bf16x8*)&Bh[(wc + t * 16 + l15) * 40 + kq * 8];
            bl[t] = *(const bf16x8*)&Bl[(wc + t * 16 + l15) * 40 + kq * 8];
        }
#pragma unroll
        for (int mt = 0; mt < 4; ++mt) {
            bf16x8 ah = *(const bf16x8*)&Ah[(wr + mt * 16 + l15) * 40 + kq * 8];
            bf16x8 al = *(const bf16x8*)&Al[(wr + mt * 16 + l15) * 40 + kq * 8];
#pragma unroll
            for (int nt = 0; nt < 4; ++nt) {
                acc[mt][nt] = __builtin_amdgcn_mfma_f32_16x16x32_bf16(ah, bh[nt], acc[mt][nt], 0, 0, 0);
                acc[mt][nt] = __builtin_amdgcn_mfma_f32_16x16x32_bf16(al, bh[nt], acc[mt][nt], 0, 0, 0);
                acc[mt][nt] = __builtin_amdgcn_mfma_f32_16x16x32_bf16(ah, bl[nt], acc[mt][nt], 0, 0, 0);
            }
        }
    }
    // epilogue: d2 = sq_i + sq_j - 2*S  (C/D: col=lane&15, row=quad*4+reg)
#pragma unroll
    for (int mt = 0; mt < 4; ++mt) {
        int rbase = row0 + wr + mt * 16 + kq * 4;
#pragma unroll
        for (int nt = 0; nt < 4; ++nt) {
            int lc = (col0 - qbase) + wc + nt * 16 + l15;    // local quarter col
            float sqc = sqb[col0 + wc + nt * 16 + l15];
            f32x4 c = acc[mt][nt];
#pragma unroll
            for (int r = 0; r < 4; ++r) {
                float sqr = sqb[rbase + r];
                d2[((size_t)b * NN + rbase + r) * QC + lc] = (sqr + sqc) - 2.f * c[r];
            }
        }
    }
}

// ---------------------------------------------------------------------------
// kNN selection over one d2 quarter: block = 64 flat rows x 512 cols.
// LDS-staged 64x128 chunks (stride 132, float4-aligned); thread (r,p) scans
// 32 cols/chunk ascending; 4-way stable merge -> cand[g][qpass][10].
__global__ __launch_bounds__(256) void knn_select_kernel(
        const float* __restrict__ d2, float* __restrict__ candD,
        int* __restrict__ candI, int qbase, int qpass) {
    int g0 = blockIdx.x * 64;                 // flat row base (b*NN+n)
    __shared__ __align__(16) float tile[64 * 132];   // 33792 B
    float* cd = tile;                          // overlay merge (after scans)
    int* ci = (int*)tile + 2560;

    int tid = threadIdx.x;
    int r = tid & 63;
    int p = tid >> 6;

    float bestd[KK];
    int besti[KK];
#pragma unroll
    for (int k = 0; k < KK; ++k) { bestd[k] = INFINITY; besti[k] = 0x7fffffff; }

    for (int ch = 0; ch < 4; ++ch) {
        __syncthreads();   // prior scan done
#pragma unroll
        for (int it = 0; it < 8; ++it) {
            int v = tid + it * 256;            // 0..2047
            int row = v >> 5, c4 = v & 31;     // 64 rows x 32 float4
            *(float4*)&tile[row * 132 + c4 * 4] =
                *(const float4*)&d2[(size_t)(g0 + row) * QC + ch * 128 + c4 * 4];
        }
        __syncthreads();
#pragma unroll
        for (int i = 0; i < 32; ++i) {
            int j = p * 32 + i;                // local col in chunk
            float d = tile[r * 132 + j];
            if (d < bestd[KK - 1]) {
                bestd[KK - 1] = d;
                besti[KK - 1] = qbase + ch * 128 + j;
#pragma unroll
                for (int s = KK - 1; s > 0; --s) {
                    if (bestd[s] < bestd[s - 1]) {
                        float td = bestd[s]; bestd[s] = bestd[s - 1]; bestd[s - 1] = td;
                        int ti = besti[s]; besti[s] = besti[s - 1]; besti[s - 1] = ti;
                    }
                }
            }
        }
    }
    __syncthreads();   // scans done before merge overlay
#pragma unroll
    for (int k = 0; k < KK; ++k) {
        cd[tid * KK + k] = bestd[k];
        ci[tid * KK + k] = besti[k];
    }
    __syncthreads();
    if (tid < 64) {
        int pq[4] = {0, 0, 0, 0};
        size_t base = ((size_t)(g0 + tid) * 4 + qpass) * KK;
        for (int s = 0; s < KK; ++s) {
            float bD = INFINITY; int bI = 0x7fffffff; int bq = 0;
#pragma unroll
            for (int q = 0; q < 4; ++q) {
                if (pq[q] < KK) {
                    int li = (q * 64 + tid) * KK + pq[q];
                    float d = cd[li]; int ii = ci[li];
                    if (d < bD || (d == bD && ii < bI)) { bD = d; bI = ii; bq = q; }
                }
            }
            pq[bq]++;
            candD[base + s] = bD;
            candI[base + s] = bI;
        }
    }
}

// ---------------------------------------------------------------------------
// merge nsplit (<=4) sorted 10-lists per row -> final top-10 indices
__global__ void knn_merge_kernel(const float* __restrict__ candD,
                                 const int* __restrict__ candI,
                                 int* __restrict__ idx, int nsplit) {
    int g = blockIdx.x * blockDim.x + threadIdx.x;
    if (g >= BN) return;
    size_t base = (size_t)g * nsplit * KK;
    int p[4] = {0, 0, 0, 0};
    int* op = idx + (size_t)g * KK;
    for (int s = 0; s < KK; ++s) {
        float bD = INFINITY; int bI = 0x7fffffff; int bq = 0;
        for (int q = 0; q < nsplit; ++q) {
            if (p[q] < KK) {
                float d = candD[base + q * KK + p[q]];
                int ii = candI[base + q * KK + p[q]];
                if (d < bD || (d == bD && ii < bI)) { bD = d; bI = ii; bq = q; }
            }
        }
        p[bq]++;
        op[s] = bI;
    }
}

// ---------------------------------------------------------------------------
// split x (fp32) into hi/lo bf16
__global__ void xsplit_kernel(const float* __restrict__ x, unsigned short* __restrict__ hi,
                              unsigned short* __restrict__ lo, int n) {
    int i = blockIdx.x * blockDim.x + threadIdx.x;
    if (i >= n) return;
    float v = x[i];
    unsigned short h = f2bf(v);
    hi[i] = h;
    lo[i] = f2bf(v - bf2f(h));
}

// ---------------------------------------------------------------------------
// Build WT[o'][2*fin] bf16: rows o'<fout -> (W1-W2) col o', else W2 col o'-fout.
__global__ void wsplit_kernel(const float* __restrict__ w, unsigned short* __restrict__ WT,
                              int fin, int fout) {
    int i = blockIdx.x * blockDim.x + threadIdx.x;
    int total = 2 * fout * fin;
    if (i >= total) return;
    int op = i % (2 * fout);
    int f = i / (2 * fout);
    float v;
    if (op < fout) v = w[(size_t)f * fout + op] - w[(size_t)(fin + f) * fout + op];
    else v = w[(size_t)(fin + f) * fout + (op - fout)];
    unsigned short h = f2bf(v);
    unsigned short l = f2bf(v - bf2f(h));
    WT[(size_t)op * (2 * fin) + f] = h;
    WT[(size_t)op * (2 * fin) + fin + f] = l;
}

// ---------------------------------------------------------------------------
// MFMA GEMM (validated round 5): A|T = xsplit @ WT^T, 3-phase bf16 split.
__global__ __launch_bounds__(256) void gemm2_mfma_kernel(
        const unsigned short* __restrict__ XSh, const unsigned short* __restrict__ XSl,
        const unsigned short* __restrict__ WT, const float* __restrict__ bias,
        float* __restrict__ Aout, float* __restrict__ Tout, int fin, int fout) {
    int m0 = blockIdx.x * 128;
    int n0 = blockIdx.y * 128;
    __shared__ __align__(16) unsigned short As[128 * 40];
    __shared__ __align__(16) unsigned short Bs[128 * 40];
    int tid = threadIdx.x;
    int lane = tid & 63;
    int wave = tid >> 6;
    int wr = (wave >> 1) * 64, wc = (wave & 1) * 64;
    int l15 = lane & 15, kq = lane >> 4;
    int w2f = 2 * fin;

    f32x4 acc[4][4];
#pragma unroll
    for (int mt = 0; mt < 4; ++mt)
#pragma unroll
        for (int nt = 0; nt < 4; ++nt) acc[mt][nt] = (f32x4){0.f, 0.f, 0.f, 0.f};

    for (int p = 0; p < 3; ++p) {
        const unsigned short* Axp = (p == 1) ? XSl : XSh;
        int bkoff = (p == 2) ? fin : 0;
        for (int kc = 0; kc < fin; kc += 32) {
            __syncthreads();
            for (int i = tid; i < 512; i += 256) {
                int row = i >> 2, sub = i & 3;
                *(uint4*)&As[row * 40 + sub * 8] =
                    *(const uint4*)&Axp[(size_t)(m0 + row) * fin + kc + sub * 8];
                *(uint4*)&Bs[row * 40 + sub * 8] =
                    *(const uint4*)&WT[(size_t)(n0 + row) * w2f + bkoff + kc + sub * 8];
            }
            __syncthreads();
            bf16x8 a[4], b[4];
#pragma unroll
            for (int t = 0; t < 4; ++t) {
                a[t] = *(const bf16x8*)&As[(wr + t * 16 + l15) * 40 + kq * 8];
                b[t] = *(const bf16x8*)&Bs[(wc + t * 16 + l15) * 40 + kq * 8];
            }
#pragma unroll
            for (int mt = 0; mt < 4; ++mt)
#pragma unroll
                for (int nt = 0; nt < 4; ++nt)
                    acc[mt][nt] = __builtin_amdgcn_mfma_f32_16x16x32_bf16(a[mt], b[nt], acc[mt][nt], 0, 0, 0);
        }
    }
#pragma unroll
    for (int mt = 0; mt < 4; ++mt) {
        int mbase = m0 + wr + mt * 16 + kq * 4;
#pragma unroll
        for (int nt = 0; nt < 4; ++nt) {
            int oc = n0 + wc + nt * 16 + l15;
            f32x4 c = acc[mt][nt];
            if (oc < fout) {
                float bv = bias[oc];
#pragma unroll
                for (int r = 0; r < 4; ++r)
                    Aout[(size_t)(mbase + r) * fout + oc] = c[r] + bv;
            } else {
                int o2 = oc - fout;
#pragma unroll
                for (int r = 0; r < 4; ++r)
                    Tout[(size_t)(mbase + r) * fout + o2] = c[r];
            }
        }
    }
}

// ---------------------------------------------------------------------------
// fp32 gemm2 (layer 0, fin=3)
__global__ __launch_bounds__(256) void gemm2_kernel(const float* __restrict__ x,
                                                    const float* __restrict__ w,
                                                    const float* __restrict__ bias,
                                                    float* __restrict__ Aout,
                                                    float* __restrict__ Tout,
                                                    int fin, int fout) {
    int m0 = blockIdx.x * 64;
    int o0 = blockIdx.y * 64;
    __shared__ float Xs[64][TF + 1];
    __shared__ float W1s[TF][64];
    __shared__ float W2s[TF][64];
    int tid = threadIdx.x;
    int tr = (tid / 16) * 4, tc = (tid % 16) * 4;
    float accA[4][4], accT[4][4];
#pragma unroll
    for (int i = 0; i < 4; ++i)
#pragma unroll
        for (int j = 0; j < 4; ++j) { accA[i][j] = 0.f; accT[i][j] = 0.f; }

    for (int f0 = 0; f0 < fin; f0 += TF) {
        __syncthreads();
        for (int l = tid; l < 64 * TF; l += 256) {
            int r = l / TF, f = l % TF;
            Xs[r][f] = (f0 + f < fin) ? x[(size_t)(m0 + r) * fin + f0 + f] : 0.f;
        }
        for (int l = tid; l < TF * 64; l += 256) {
            int f = l / 64, o = l % 64;
            bool ok = (f0 + f < fin);
            W1s[f][o] = ok ? w[(size_t)(f0 + f) * fout + o0 + o] : 0.f;
            W2s[f][o] = ok ? w[(size_t)(f0 + f + fin) * fout + o0 + o] : 0.f;
        }
        __syncthreads();
#pragma unroll
        for (int f = 0; f < TF; ++f) {
            float a[4], w1[4], w2[4];
#pragma unroll
            for (int i = 0; i < 4; ++i) a[i] = Xs[tr + i][f];
#pragma unroll
            for (int j = 0; j < 4; ++j) { w1[j] = W1s[f][tc + j]; w2[j] = W2s[f][tc + j]; }
#pragma unroll
            for (int i = 0; i < 4; ++i)
#pragma unroll
                for (int j = 0; j < 4; ++j) {
                    accA[i][j] += a[i] * (w1[j] - w2[j]);
                    accT[i][j] += a[i] * w2[j];
                }
        }
    }
#pragma unroll
    for (int i = 0; i < 4; ++i)
#pragma unroll
        for (int j = 0; j < 4; ++j) {
            int m = m0 + tr + i, o = o0 + tc + j;
            Aout[(size_t)m * fout + o] = accA[i][j] + bias[o];
            Tout[(size_t)m * fout + o] = accT[i][j];
        }
}

// ---------------------------------------------------------------------------
__global__ void gathermax_kernel(const float* __restrict__ A, const float* __restrict__ T,
                                 const int* __restrict__ idx, float* __restrict__ out,
                                 int fout) {
    int pn = blockIdx.x;
    int b = pn / NN;
    int o = blockIdx.y * 64 + threadIdx.x;
    const int* ip = idx + (size_t)pn * KK;
    const float* Tb = T + (size_t)b * NN * fout;
    float m = -INFINITY;
#pragma unroll
    for (int k = 0; k < KK; ++k) {
        int j = ip[k];
        m = fmaxf(m, Tb[(size_t)j * fout + o]);
    }
    float h = A[(size_t)pn * fout + o] + m;
    out[(size_t)pn * fout + o] = h > 0.f ? h : 0.2f * h;
}

// ---------------------------------------------------------------------------
__global__ void gmax_kernel(const float* __restrict__ h, float* __restrict__ g) {
    int b = blockIdx.y;
    int o = blockIdx.x * 256 + threadIdx.x;
    const float* hp = h + (size_t)b * NN * 1024 + o;
    float m = -INFINITY;
    for (int n = 0; n < NN; ++n) m = fmaxf(m, hp[(size_t)n * 1024]);
    g[(size_t)b * 1024 + o] = m;
}

// ---------------------------------------------------------------------------
__global__ __launch_bounds__(128) void mlp_kernel(const float* __restrict__ g,
                                                  const float* __restrict__ m0w, const float* __restrict__ m0b,
                                                  const float* __restrict__ m1w, const float* __restrict__ m1b,
                                                  const float* __restrict__ m2w, const float* __restrict__ m2b,
                                                  float* __restrict__ out) {
    __shared__ float gs[1024];
    __shared__ float h1[128];
    __shared__ float h2[64];
    int b = blockIdx.x, t = threadIdx.x;
    for (int i = t; i < 1024; i += 128) gs[i] = g[(size_t)b * 1024 + i];
    __syncthreads();
    float s = m0b[t];
    for (int f = 0; f < 1024; ++f) s += gs[f] * m0w[(size_t)f * 128 + t];
    h1[t] = s;
    __syncthreads();
    if (t < 64) {
        float s2 = m1b[t];
        for (int f = 0; f < 128; ++f) s2 += h1[f] * m1w[(size_t)f * 64 + t];
        h2[t] = s2;
    }
    __syncthreads();
    if (t == 0) {
        float s3 = m2b[0];
        for (int f = 0; f < 64; ++f) s3 += h2[f] * m2w[f];
        out[b] = s3;
    }
}

// ---------------------------------------------------------------------------
extern "C" void kernel_launch(void* const* d_in, const int* in_sizes, int n_in,
                              void* d_out, int out_size, void* d_ws, size_t ws_size,
                              hipStream_t stream) {
    const float* x0 = (const float*)d_in[0];
    const float* w[5], * bi[5];
    for (int i = 0; i < 5; ++i) { w[i] = (const float*)d_in[1 + 2 * i]; bi[i] = (const float*)d_in[2 + 2 * i]; }
    const float* m0w = (const float*)d_in[11]; const float* m0b = (const float*)d_in[12];
    const float* m1w = (const float*)d_in[13]; const float* m1b = (const float*)d_in[14];
    const float* m2w = (const float*)d_in[15]; const float* m2b = (const float*)d_in[16];

    float* X0 = (float*)d_ws;
    float* X1 = X0 + (size_t)BN * 1024;
    float* T  = X1 + (size_t)BN * 1024;
    float* SQ = T  + (size_t)BN * 1024;
    int*   IDX = (int*)(SQ + BN);
    float* G  = (float*)(IDX + (size_t)BN * KK);
    unsigned short* XSh = (unsigned short*)(G + (size_t)BB * 1024);
    unsigned short* XSl = XSh + (size_t)BN * 512;   // max fin = 512
    unsigned short* WT  = XSl + (size_t)BN * 512;   // max 2*1024 x 2*512 bf16

    // overlays on T (T written only after kNN done):
    float* candD = T;                                // BN*4*KK floats (2.6 MB)
    int*   candI = (int*)(T + (size_t)BN * 4 * KK);  // 2.6 MB
    float* D2    = T + (size_t)4 * 1024 * 1024;      // quarter d2: BN*512 floats (33.5 MB)

    const int fouts[5] = {64, 128, 256, 512, 1024};
    const float* cur = x0;
    int fin = 3;
    float* bufs[2] = {X0, X1};

    for (int l = 0; l < 5; ++l) {
        int fout = fouts[l];
        float* nxt = bufs[l & 1];

        sqnorm_kernel<<<(BN + 255) / 256, 256, 0, stream>>>(cur, SQ, fin);

        if (l == 0) {
            dim3 kg(NN / TR, SPLIT, BB);
            knn_part_kernel<<<kg, 256, 0, stream>>>(cur, SQ, candD, candI, fin);
            knn_merge_kernel<<<(BN + 255) / 256, 256, 0, stream>>>(candD, candI, IDX, SPLIT);

            dim3 gg(BN / 64, fout / 64);
            gemm2_kernel<<<gg, 256, 0, stream>>>(cur, w[l], bi[l], nxt, T, fin, fout);
        } else {
            int nx = BN * fin;
            xsplit_kernel<<<(nx + 255) / 256, 256, 0, stream>>>(cur, XSh, XSl, nx);

            dim3 gg2(NN / 128, QC / 128, BB);
            for (int q = 0; q < 4; ++q) {
                knn_gram_kernel<<<gg2, 256, 0, stream>>>(XSh, XSl, SQ, D2, fin, q * QC);
                knn_select_kernel<<<BN / 64, 256, 0, stream>>>(D2, candD, candI, q * QC, q);
            }
            knn_merge_kernel<<<(BN + 255) / 256, 256, 0, stream>>>(candD, candI, IDX, 4);

            int nw = 2 * fout * fin;
            wsplit_kernel<<<(nw + 255) / 256, 256, 0, stream>>>(w[l], WT, fin, fout);
            dim3 gg(BN / 128, (2 * fout) / 128);
            gemm2_mfma_kernel<<<gg, 256, 0, stream>>>(XSh, XSl, WT, bi[l], nxt, T, fin, fout);
        }

        dim3 mg(BN, fout / 64);
        gathermax_kernel<<<mg, 64, 0, stream>>>(nxt, T, IDX, nxt, fout);

        cur = nxt;
        fin = fout;
    }

    dim3 xg(1024 / 256, BB);
    gmax_kernel<<<xg, 256, 0, stream>>>(cur, G);

    mlp_kernel<<<BB, 128, 0, stream>>>(G, m0w, m0b, m1w, m1b, m2w, m2b, (float*)d_out);
}

// Round 11
// 2037.430 us; speedup vs baseline: 1.2406x; 1.1749x over previous
//
#include <hip/hip_runtime.h>
#include <hip/hip_bf16.h>
#include <math.h>

#define BB 8
#define NN 2048
#define KK 10
#define BN (BB * NN)

#define TR 64
#define TC 64
#define TF 32
#define SPLIT 4
#define CPS (NN / SPLIT)   // 512 cols per split-block (fp32 layer-0 path)
#define QC 512             // cols per d2 quarter-pass (MFMA knn)

typedef __attribute__((ext_vector_type(8))) short bf16x8;
typedef __attribute__((ext_vector_type(4))) float f32x4;

__device__ inline unsigned short f2bf(float f) {
    unsigned int u = __float_as_uint(f);
    unsigned int r = u + 0x7fffu + ((u >> 16) & 1u);
    return (unsigned short)(r >> 16);
}
__device__ inline float bf2f(unsigned short h) {
    return __uint_as_float((unsigned int)h << 16);
}

// ---------------------------------------------------------------------------
// sq[i] = sum_f x[i,f]^2   (layer 0 only; layers 1-4 fused into xsplit)
__global__ void sqnorm_kernel(const float* __restrict__ x, float* __restrict__ sq, int F) {
    int i = blockIdx.x * blockDim.x + threadIdx.x;
    if (i >= BN) return;
    const float* xp = x + (size_t)i * F;
    float s = 0.f;
    for (int f = 0; f < F; ++f) { float v = xp[f]; s += v * v; }
    sq[i] = s;
}

// ---------------------------------------------------------------------------
// kNN fp32 path (layer 0, F=3 only) — validated round 3
__global__ __launch_bounds__(256, 4) void knn_part_kernel(const float* __restrict__ x,
                                                          const float* __restrict__ sq,
                                                          float* __restrict__ candD,
                                                          int* __restrict__ candI, int F) {
    int b = blockIdx.z;
    int row0 = blockIdx.x * TR;
    int colbase = blockIdx.y * CPS;
    const float* xb = x + (size_t)b * NN * F;
    const float* sqb = sq + (size_t)b * NN;

    __shared__ float smem[TF * 68 * 2 + TR * 65];
    float* As = smem;
    float* Bs = smem + TF * 68;
    float* Ds = smem + TF * 68 * 2;

    int tid = threadIdx.x;
    int tr = (tid / 16) * 4;
    int tc = (tid % 16) * 4;
    int srow = tid & 63;
    int squart = tid >> 6;
    int scol0 = squart * 16;

    float bestd[KK];
    int bestidx[KK];
#pragma unroll
    for (int k = 0; k < KK; ++k) { bestd[k] = INFINITY; bestidx[k] = 0x7fffffff; }

    for (int ct = 0; ct < CPS; ct += TC) {
        int col0 = colbase + ct;
        float acc[4][4];
#pragma unroll
        for (int i = 0; i < 4; ++i)
#pragma unroll
            for (int j = 0; j < 4; ++j) acc[i][j] = 0.f;

        for (int f0 = 0; f0 < F; f0 += TF) {
            __syncthreads();
            for (int l = tid; l < TR * TF; l += 256) {
                int r = l / TF, f = l % TF;
                As[f * 68 + r] = (f0 + f < F) ? xb[(size_t)(row0 + r) * F + f0 + f] : 0.f;
                Bs[f * 68 + r] = (f0 + f < F) ? xb[(size_t)(col0 + r) * F + f0 + f] : 0.f;
            }
            __syncthreads();
#pragma unroll
            for (int f = 0; f < TF; ++f) {
                float a[4], bv[4];
#pragma unroll
                for (int i = 0; i < 4; ++i) a[i] = As[f * 68 + tr + i];
#pragma unroll
                for (int j = 0; j < 4; ++j) bv[j] = Bs[f * 68 + tc + j];
#pragma unroll
                for (int i = 0; i < 4; ++i)
#pragma unroll
                    for (int j = 0; j < 4; ++j) acc[i][j] += a[i] * bv[j];
            }
        }
        __syncthreads();
#pragma unroll
        for (int i = 0; i < 4; ++i) {
            float sr = sqb[row0 + tr + i];
#pragma unroll
            for (int j = 0; j < 4; ++j) {
                Ds[(tr + i) * 65 + tc + j] = (sr + sqb[col0 + tc + j]) - 2.f * acc[i][j];
            }
        }
        __syncthreads();
#pragma unroll
        for (int cc = 0; cc < 16; ++cc) {
            int c = scol0 + cc;
            float d = Ds[srow * 65 + c];
            if (d < bestd[KK - 1]) {
                bestd[KK - 1] = d;
                bestidx[KK - 1] = col0 + c;
#pragma unroll
                for (int p = KK - 1; p > 0; --p) {
                    if (bestd[p] < bestd[p - 1]) {
                        float td = bestd[p]; bestd[p] = bestd[p - 1]; bestd[p - 1] = td;
                        int ti = bestidx[p]; bestidx[p] = bestidx[p - 1]; bestidx[p - 1] = ti;
                    }
                }
            }
        }
    }
    __syncthreads();
    float* candd_s = smem;
    int* candi_s = (int*)(smem + 256 * KK);
#pragma unroll
    for (int k = 0; k < KK; ++k) {
        candd_s[tid * KK + k] = bestd[k];
        candi_s[tid * KK + k] = bestidx[k];
    }
    __syncthreads();
    if (tid < TR) {
        int p[4] = {0, 0, 0, 0};
        size_t base = ((size_t)((size_t)b * NN + row0 + tid) * SPLIT + blockIdx.y) * KK;
        for (int s = 0; s < KK; ++s) {
            float bD = INFINITY; int bI = 0x7fffffff; int bq = 0;
#pragma unroll
            for (int q = 0; q < 4; ++q) {
                if (p[q] < KK) {
                    int li = (q * 64 + tid) * KK + p[q];
                    float d = candd_s[li]; int ii = candi_s[li];
                    if (d < bD || (d == bD && ii < bI)) { bD = d; bI = ii; bq = q; }
                }
            }
            p[bq]++;
            candD[base + s] = bD;
            candI[base + s] = bI;
        }
    }
}

// ---------------------------------------------------------------------------
// kNN Gram GEMM (layers 1-4): PURE MFMA GEMM writing d2 tiles to global
// scratch (quarter of columns per pass). Round-8 proven staging.
__global__ __launch_bounds__(256) void knn_gram_kernel(
        const unsigned short* __restrict__ xh, const unsigned short* __restrict__ xl,
        const float* __restrict__ sq, float* __restrict__ d2, int F, int qbase) {
    int b = blockIdx.z;
    int row0 = blockIdx.x * 128;
    int col0 = qbase + blockIdx.y * 128;          // global col
    const unsigned short* xhb = xh + (size_t)b * NN * F;
    const unsigned short* xlb = xl + (size_t)b * NN * F;
    const float* sqb = sq + (size_t)b * NN;

    __shared__ __align__(16) unsigned short AsB[4 * 128 * 40];   // 40 KB
    unsigned short* Ah = AsB;
    unsigned short* Al = Ah + 128 * 40;
    unsigned short* Bh = Al + 128 * 40;
    unsigned short* Bl = Bh + 128 * 40;

    int tid = threadIdx.x;
    int lane = tid & 63;
    int wave = tid >> 6;
    int wr = (wave >> 1) * 64, wc = (wave & 1) * 64;
    int l15 = lane & 15, kq = lane >> 4;

    f32x4 acc[4][4];
#pragma unroll
    for (int mt = 0; mt < 4; ++mt)
#pragma unroll
        for (int nt = 0; nt < 4; ++nt) acc[mt][nt] = (f32x4){0.f, 0.f, 0.f, 0.f};

    for (int kc = 0; kc < F; kc += 32) {
        __syncthreads();
#pragma unroll
        for (int it = 0; it < 8; ++it) {
            int i = tid + it * 256;            // 0..2047
            int tile = i >> 9;                 // 512 uint4 per tile
            int rs = i & 511;
            int row = rs >> 2, sub = rs & 3;
            const unsigned short* src;
            unsigned short* dst;
            if (tile == 0)      { src = xhb + (size_t)(row0 + row) * F; dst = Ah; }
            else if (tile == 1) { src = xlb + (size_t)(row0 + row) * F; dst = Al; }
            else if (tile == 2) { src = xhb + (size_t)(col0 + row) * F; dst = Bh; }
            else                { src = xlb + (size_t)(col0 + row) * F; dst = Bl; }
            *(uint4*)&dst[row * 40 + sub * 8] = *(const uint4*)&src[kc + sub * 8];
        }
        __syncthreads();
        bf16x8 bh[4], bl[4];
#pragma unroll
        for (int t = 0; t < 4; ++t) {
            bh[t] = *(const bf16x8*)&Bh[(wc + t * 16 + l15) * 40 + kq * 8];
            bl[t] = *(const bf16x8*)&Bl[(wc + t * 16 + l15) * 40 + kq * 8];
        }
#pragma unroll
        for (int mt = 0; mt < 4; ++mt) {
            bf16x8 ah = *(const bf16x8*)&Ah[(wr + mt * 16 + l15) * 40 + kq * 8];
            bf16x8 al = *(const bf16x8*)&Al[(wr + mt * 16 + l15) * 40 + kq * 8];
#pragma unroll
            for (int nt = 0; nt < 4; ++nt) {
                acc[mt][nt] = __builtin_amdgcn_mfma_f32_16x16x32_bf16(ah, bh[nt], acc[mt][nt], 0, 0, 0);
                acc[mt][nt] = __builtin_amdgcn_mfma_f32_16x16x32_bf16(al, bh[nt], acc[mt][nt], 0, 0, 0);
                acc[mt][nt] = __builtin_amdgcn_mfma_f32_16x16x32_bf16(ah, bl[nt], acc[mt][nt], 0, 0, 0);
            }
        }
    }
#pragma unroll
    for (int mt = 0; mt < 4; ++mt) {
        int rbase = row0 + wr + mt * 16 + kq * 4;
#pragma unroll
        for (int nt = 0; nt < 4; ++nt) {
            int lc = (col0 - qbase) + wc + nt * 16 + l15;    // local quarter col
            float sqc = sqb[col0 + wc + nt * 16 + l15];
            f32x4 c = acc[mt][nt];
#pragma unroll
            for (int r = 0; r < 4; ++r) {
                float sqr = sqb[rbase + r];
                d2[((size_t)b * NN + rbase + r) * QC + lc] = (sqr + sqc) - 2.f * c[r];
            }
        }
    }
}

// ---------------------------------------------------------------------------
// kNN selection over one d2 quarter (validated round 10).
__global__ __launch_bounds__(256) void knn_select_kernel(
        const float* __restrict__ d2, float* __restrict__ candD,
        int* __restrict__ candI, int qbase, int qpass) {
    int g0 = blockIdx.x * 64;
    __shared__ __align__(16) float tile[64 * 132];
    float* cd = tile;
    int* ci = (int*)tile + 2560;

    int tid = threadIdx.x;
    int r = tid & 63;
    int p = tid >> 6;

    float bestd[KK];
    int besti[KK];
#pragma unroll
    for (int k = 0; k < KK; ++k) { bestd[k] = INFINITY; besti[k] = 0x7fffffff; }

    for (int ch = 0; ch < 4; ++ch) {
        __syncthreads();
#pragma unroll
        for (int it = 0; it < 8; ++it) {
            int v = tid + it * 256;
            int row = v >> 5, c4 = v & 31;
            *(float4*)&tile[row * 132 + c4 * 4] =
                *(const float4*)&d2[(size_t)(g0 + row) * QC + ch * 128 + c4 * 4];
        }
        __syncthreads();
#pragma unroll
        for (int i = 0; i < 32; ++i) {
            int j = p * 32 + i;
            float d = tile[r * 132 + j];
            if (d < bestd[KK - 1]) {
                bestd[KK - 1] = d;
                besti[KK - 1] = qbase + ch * 128 + j;
#pragma unroll
                for (int s = KK - 1; s > 0; --s) {
                    if (bestd[s] < bestd[s - 1]) {
                        float td = bestd[s]; bestd[s] = bestd[s - 1]; bestd[s - 1] = td;
                        int ti = besti[s]; besti[s] = besti[s - 1]; besti[s - 1] = ti;
                    }
                }
            }
        }
    }
    __syncthreads();
#pragma unroll
    for (int k = 0; k < KK; ++k) {
        cd[tid * KK + k] = bestd[k];
        ci[tid * KK + k] = besti[k];
    }
    __syncthreads();
    if (tid < 64) {
        int pq[4] = {0, 0, 0, 0};
        size_t base = ((size_t)(g0 + tid) * 4 + qpass) * KK;
        for (int s = 0; s < KK; ++s) {
            float bD = INFINITY; int bI = 0x7fffffff; int bq = 0;
#pragma unroll
            for (int q = 0; q < 4; ++q) {
                if (pq[q] < KK) {
                    int li = (q * 64 + tid) * KK + pq[q];
                    float d = cd[li]; int ii = ci[li];
                    if (d < bD || (d == bD && ii < bI)) { bD = d; bI = ii; bq = q; }
                }
            }
            pq[bq]++;
            candD[base + s] = bD;
            candI[base + s] = bI;
        }
    }
}

// ---------------------------------------------------------------------------
// merge nsplit (<=4) sorted 10-lists per row -> final top-10 indices
__global__ void knn_merge_kernel(const float* __restrict__ candD,
                                 const int* __restrict__ candI,
                                 int* __restrict__ idx, int nsplit) {
    int g = blockIdx.x * blockDim.x + threadIdx.x;
    if (g >= BN) return;
    size_t base = (size_t)g * nsplit * KK;
    int p[4] = {0, 0, 0, 0};
    int* op = idx + (size_t)g * KK;
    for (int s = 0; s < KK; ++s) {
        float bD = INFINITY; int bI = 0x7fffffff; int bq = 0;
        for (int q = 0; q < nsplit; ++q) {
            if (p[q] < KK) {
                float d = candD[base + q * KK + p[q]];
                int ii = candI[base + q * KK + p[q]];
                if (d < bD || (d == bD && ii < bI)) { bD = d; bI = ii; bq = q; }
            }
        }
        p[bq]++;
        op[s] = bI;
    }
}

// ---------------------------------------------------------------------------
// Fused: split x into hi/lo bf16 AND compute sq row-norms (one x read).
// One wave per row (F >= 64, multiple of 64 not required but f-strided).
__global__ __launch_bounds__(256) void xsplit_sq_kernel(
        const float* __restrict__ x, unsigned short* __restrict__ hi,
        unsigned short* __restrict__ lo, float* __restrict__ sq, int F) {
    int row = blockIdx.x * 4 + (threadIdx.x >> 6);
    int lane = threadIdx.x & 63;
    const float* xp = x + (size_t)row * F;
    float s = 0.f;
    for (int f = lane; f < F; f += 64) {
        float v = xp[f];
        unsigned short h = f2bf(v);
        hi[(size_t)row * F + f] = h;
        lo[(size_t)row * F + f] = f2bf(v - bf2f(h));
        s += v * v;
    }
#pragma unroll
    for (int off = 32; off > 0; off >>= 1) s += __shfl_down(s, off);
    if (lane == 0) sq[row] = s;
}

// ---------------------------------------------------------------------------
// Build WT[o'][2*fin] bf16: rows o'<fout -> (W1-W2) col o', else W2 col o'-fout.
__global__ void wsplit_kernel(const float* __restrict__ w, unsigned short* __restrict__ WT,
                              int fin, int fout) {
    int i = blockIdx.x * blockDim.x + threadIdx.x;
    int total = 2 * fout * fin;
    if (i >= total) return;
    int op = i % (2 * fout);
    int f = i / (2 * fout);
    float v;
    if (op < fout) v = w[(size_t)f * fout + op] - w[(size_t)(fin + f) * fout + op];
    else v = w[(size_t)(fin + f) * fout + (op - fout)];
    unsigned short h = f2bf(v);
    unsigned short l = f2bf(v - bf2f(h));
    WT[(size_t)op * (2 * fin) + f] = h;
    WT[(size_t)op * (2 * fin) + fin + f] = l;
}

// ---------------------------------------------------------------------------
// MFMA GEMM (validated round 5): A|T = xsplit @ WT^T, 3-phase bf16 split.
__global__ __launch_bounds__(256) void gemm2_mfma_kernel(
        const unsigned short* __restrict__ XSh, const unsigned short* __restrict__ XSl,
        const unsigned short* __restrict__ WT, const float* __restrict__ bias,
        float* __restrict__ Aout, float* __restrict__ Tout, int fin, int fout) {
    int m0 = blockIdx.x * 128;
    int n0 = blockIdx.y * 128;
    __shared__ __align__(16) unsigned short As[128 * 40];
    __shared__ __align__(16) unsigned short Bs[128 * 40];
    int tid = threadIdx.x;
    int lane = tid & 63;
    int wave = tid >> 6;
    int wr = (wave >> 1) * 64, wc = (wave & 1) * 64;
    int l15 = lane & 15, kq = lane >> 4;
    int w2f = 2 * fin;

    f32x4 acc[4][4];
#pragma unroll
    for (int mt = 0; mt < 4; ++mt)
#pragma unroll
        for (int nt = 0; nt < 4; ++nt) acc[mt][nt] = (f32x4){0.f, 0.f, 0.f, 0.f};

    for (int p = 0; p < 3; ++p) {
        const unsigned short* Axp = (p == 1) ? XSl : XSh;
        int bkoff = (p == 2) ? fin : 0;
        for (int kc = 0; kc < fin; kc += 32) {
            __syncthreads();
            for (int i = tid; i < 512; i += 256) {
                int row = i >> 2, sub = i & 3;
                *(uint4*)&As[row * 40 + sub * 8] =
                    *(const uint4*)&Axp[(size_t)(m0 + row) * fin + kc + sub * 8];
                *(uint4*)&Bs[row * 40 + sub * 8] =
                    *(const uint4*)&WT[(size_t)(n0 + row) * w2f + bkoff + kc + sub * 8];
            }
            __syncthreads();
            bf16x8 a[4], b[4];
#pragma unroll
            for (int t = 0; t < 4; ++t) {
                a[t] = *(const bf16x8*)&As[(wr + t * 16 + l15) * 40 + kq * 8];
                b[t] = *(const bf16x8*)&Bs[(wc + t * 16 + l15) * 40 + kq * 8];
            }
#pragma unroll
            for (int mt = 0; mt < 4; ++mt)
#pragma unroll
                for (int nt = 0; nt < 4; ++nt)
                    acc[mt][nt] = __builtin_amdgcn_mfma_f32_16x16x32_bf16(a[mt], b[nt], acc[mt][nt], 0, 0, 0);
        }
    }
#pragma unroll
    for (int mt = 0; mt < 4; ++mt) {
        int mbase = m0 + wr + mt * 16 + kq * 4;
#pragma unroll
        for (int nt = 0; nt < 4; ++nt) {
            int oc = n0 + wc + nt * 16 + l15;
            f32x4 c = acc[mt][nt];
            if (oc < fout) {
                float bv = bias[oc];
#pragma unroll
                for (int r = 0; r < 4; ++r)
                    Aout[(size_t)(mbase + r) * fout + oc] = c[r] + bv;
            } else {
                int o2 = oc - fout;
#pragma unroll
                for (int r = 0; r < 4; ++r)
                    Tout[(size_t)(mbase + r) * fout + o2] = c[r];
            }
        }
    }
}

// ---------------------------------------------------------------------------
// fp32 gemm2 (layer 0, fin=3)
__global__ __launch_bounds__(256) void gemm2_kernel(const float* __restrict__ x,
                                                    const float* __restrict__ w,
                                                    const float* __restrict__ bias,
                                                    float* __restrict__ Aout,
                                                    float* __restrict__ Tout,
                                                    int fin, int fout) {
    int m0 = blockIdx.x * 64;
    int o0 = blockIdx.y * 64;
    __shared__ float Xs[64][TF + 1];
    __shared__ float W1s[TF][64];
    __shared__ float W2s[TF][64];
    int tid = threadIdx.x;
    int tr = (tid / 16) * 4, tc = (tid % 16) * 4;
    float accA[4][4], accT[4][4];
#pragma unroll
    for (int i = 0; i < 4; ++i)
#pragma unroll
        for (int j = 0; j < 4; ++j) { accA[i][j] = 0.f; accT[i][j] = 0.f; }

    for (int f0 = 0; f0 < fin; f0 += TF) {
        __syncthreads();
        for (int l = tid; l < 64 * TF; l += 256) {
            int r = l / TF, f = l % TF;
            Xs[r][f] = (f0 + f < fin) ? x[(size_t)(m0 + r) * fin + f0 + f] : 0.f;
        }
        for (int l = tid; l < TF * 64; l += 256) {
            int f = l / 64, o = l % 64;
            bool ok = (f0 + f < fin);
            W1s[f][o] = ok ? w[(size_t)(f0 + f) * fout + o0 + o] : 0.f;
            W2s[f][o] = ok ? w[(size_t)(f0 + f + fin) * fout + o0 + o] : 0.f;
        }
        __syncthreads();
#pragma unroll
        for (int f = 0; f < TF; ++f) {
            float a[4], w1[4], w2[4];
#pragma unroll
            for (int i = 0; i < 4; ++i) a[i] = Xs[tr + i][f];
#pragma unroll
            for (int j = 0; j < 4; ++j) { w1[j] = W1s[f][tc + j]; w2[j] = W2s[f][tc + j]; }
#pragma unroll
            for (int i = 0; i < 4; ++i)
#pragma unroll
                for (int j = 0; j < 4; ++j) {
                    accA[i][j] += a[i] * (w1[j] - w2[j]);
                    accT[i][j] += a[i] * w2[j];
                }
        }
    }
#pragma unroll
    for (int i = 0; i < 4; ++i)
#pragma unroll
        for (int j = 0; j < 4; ++j) {
            int m = m0 + tr + i, o = o0 + tc + j;
            Aout[(size_t)m * fout + o] = accA[i][j] + bias[o];
            Tout[(size_t)m * fout + o] = accT[i][j];
        }
}

// ---------------------------------------------------------------------------
// Grid-stride gathermax: out[e] = lrelu(A[e] + max_k T[(b*NN+idx[pn][k])*fout + o])
// fout is a power of two -> shift/mask addressing; idx reads wave-uniform.
__global__ __launch_bounds__(256) void gathermax_kernel(
        const float* __restrict__ A, const float* __restrict__ T,
        const int* __restrict__ idx, float* __restrict__ out,
        int shift, int total) {
    int fm = (1 << shift) - 1;
    int stride = gridDim.x * 256;
    for (int e = blockIdx.x * 256 + threadIdx.x; e < total; e += stride) {
        int pn = e >> shift;
        int o = e & fm;
        int b = pn >> 11;                 // NN = 2048
        const int* ip = idx + (size_t)pn * KK;
        float m = -INFINITY;
#pragma unroll
        for (int k = 0; k < KK; ++k) {
            int j = ip[k];
            m = fmaxf(m, T[(((size_t)b << 11) + j) * (fm + 1) + o]);
        }
        float h = A[e] + m;
        out[e] = h > 0.f ? h : 0.2f * h;
    }
}

// ---------------------------------------------------------------------------
// Two-pass global max over N.  Pass 1: 128-row chunks -> partials.
__global__ void gmax1_kernel(const float* __restrict__ h, float* __restrict__ gp) {
    int b = blockIdx.y;
    int chunk = blockIdx.z;
    int o = blockIdx.x * 256 + threadIdx.x;
    const float* hp = h + ((size_t)b * NN + chunk * 128) * 1024 + o;
    float m = -INFINITY;
    for (int n = 0; n < 128; ++n) m = fmaxf(m, hp[(size_t)n * 1024]);
    gp[((size_t)chunk * BB + b) * 1024 + o] = m;
}
__global__ void gmax2_kernel(const float* __restrict__ gp, float* __restrict__ g) {
    int b = blockIdx.y;
    int o = blockIdx.x * 256 + threadIdx.x;
    float m = -INFINITY;
    for (int c = 0; c < 16; ++c) m = fmaxf(m, gp[((size_t)c * BB + b) * 1024 + o]);
    g[(size_t)b * 1024 + o] = m;
}

// ---------------------------------------------------------------------------
__global__ __launch_bounds__(128) void mlp_kernel(const float* __restrict__ g,
                                                  const float* __restrict__ m0w, const float* __restrict__ m0b,
                                                  const float* __restrict__ m1w, const float* __restrict__ m1b,
                                                  const float* __restrict__ m2w, const float* __restrict__ m2b,
                                                  float* __restrict__ out) {
    __shared__ float gs[1024];
    __shared__ float h1[128];
    __shared__ float h2[64];
    int b = blockIdx.x, t = threadIdx.x;
    for (int i = t; i < 1024; i += 128) gs[i] = g[(size_t)b * 1024 + i];
    __syncthreads();
    float s = m0b[t];
    for (int f = 0; f < 1024; ++f) s += gs[f] * m0w[(size_t)f * 128 + t];
    h1[t] = s;
    __syncthreads();
    if (t < 64) {
        float s2 = m1b[t];
        for (int f = 0; f < 128; ++f) s2 += h1[f] * m1w[(size_t)f * 64 + t];
        h2[t] = s2;
    }
    __syncthreads();
    if (t == 0) {
        float s3 = m2b[0];
        for (int f = 0; f < 64; ++f) s3 += h2[f] * m2w[f];
        out[b] = s3;
    }
}

// ---------------------------------------------------------------------------
extern "C" void kernel_launch(void* const* d_in, const int* in_sizes, int n_in,
                              void* d_out, int out_size, void* d_ws, size_t ws_size,
                              hipStream_t stream) {
    const float* x0 = (const float*)d_in[0];
    const float* w[5], * bi[5];
    for (int i = 0; i < 5; ++i) { w[i] = (const float*)d_in[1 + 2 * i]; bi[i] = (const float*)d_in[2 + 2 * i]; }
    const float* m0w = (const float*)d_in[11]; const float* m0b = (const float*)d_in[12];
    const float* m1w = (const float*)d_in[13]; const float* m1b = (const float*)d_in[14];
    const float* m2w = (const float*)d_in[15]; const float* m2b = (const float*)d_in[16];

    float* X0 = (float*)d_ws;
    float* X1 = X0 + (size_t)BN * 1024;
    float* T  = X1 + (size_t)BN * 1024;
    float* SQ = T  + (size_t)BN * 1024;
    int*   IDX = (int*)(SQ + BN);
    float* G  = (float*)(IDX + (size_t)BN * KK);
    unsigned short* XSh = (unsigned short*)(G + (size_t)BB * 1024);
    unsigned short* XSl = XSh + (size_t)BN * 512;   // max fin = 512
    unsigned short* WT  = XSl + (size_t)BN * 512;   // max 2*1024 x 2*512 bf16

    // overlays on T (T written only after kNN done):
    float* candD = T;                                // BN*4*KK floats
    int*   candI = (int*)(T + (size_t)BN * 4 * KK);
    float* D2    = T + (size_t)4 * 1024 * 1024;      // quarter d2: BN*512 floats
    float* GP    = D2;                               // gmax partials (after knn done)

    const int fouts[5] = {64, 128, 256, 512, 1024};
    const int shifts[5] = {6, 7, 8, 9, 10};
    const float* cur = x0;
    int fin = 3;
    float* bufs[2] = {X0, X1};

    for (int l = 0; l < 5; ++l) {
        int fout = fouts[l];
        float* nxt = bufs[l & 1];

        if (l == 0) {
            sqnorm_kernel<<<(BN + 255) / 256, 256, 0, stream>>>(cur, SQ, fin);

            dim3 kg(NN / TR, SPLIT, BB);
            knn_part_kernel<<<kg, 256, 0, stream>>>(cur, SQ, candD, candI, fin);
            knn_merge_kernel<<<(BN + 255) / 256, 256, 0, stream>>>(candD, candI, IDX, SPLIT);

            dim3 gg(BN / 64, fout / 64);
            gemm2_kernel<<<gg, 256, 0, stream>>>(cur, w[l], bi[l], nxt, T, fin, fout);
        } else {
            xsplit_sq_kernel<<<BN / 4, 256, 0, stream>>>(cur, XSh, XSl, SQ, fin);

            dim3 gg2(NN / 128, QC / 128, BB);
            for (int q = 0; q < 4; ++q) {
                knn_gram_kernel<<<gg2, 256, 0, stream>>>(XSh, XSl, SQ, D2, fin, q * QC);
                knn_select_kernel<<<BN / 64, 256, 0, stream>>>(D2, candD, candI, q * QC, q);
            }
            knn_merge_kernel<<<(BN + 255) / 256, 256, 0, stream>>>(candD, candI, IDX, 4);

            int nw = 2 * fout * fin;
            wsplit_kernel<<<(nw + 255) / 256, 256, 0, stream>>>(w[l], WT, fin, fout);
            dim3 gg(BN / 128, (2 * fout) / 128);
            gemm2_mfma_kernel<<<gg, 256, 0, stream>>>(XSh, XSl, WT, bi[l], nxt, T, fin, fout);
        }

        gathermax_kernel<<<2048, 256, 0, stream>>>(nxt, T, IDX, nxt, shifts[l], BN * fout);

        cur = nxt;
        fin = fout;
    }

    dim3 x1(1024 / 256, BB, 16);
    gmax1_kernel<<<x1, 256, 0, stream>>>(cur, GP);
    dim3 x2(1024 / 256, BB);
    gmax2_kernel<<<x2, 256, 0, stream>>>(GP, G);

    mlp_kernel<<<BB, 128, 0, stream>>>(G, m0w, m0b, m1w, m1b, m2w, m2b, (float*)d_out);
}

// Round 12
// 1801.211 us; speedup vs baseline: 1.4034x; 1.1311x over previous
//
#include <hip/hip_runtime.h>
#include <hip/hip_bf16.h>
#include <math.h>

#define BB 8
#define NN 2048
#define KK 10
#define BN (BB * NN)
#define HC 1024            // cols per d2 half (2 halves = full 2048)

typedef __attribute__((ext_vector_type(8))) short bf16x8;
typedef __attribute__((ext_vector_type(4))) float f32x4;

__device__ inline unsigned short f2bf(float f) {
    unsigned int u = __float_as_uint(f);
    unsigned int r = u + 0x7fffu + ((u >> 16) & 1u);
    return (unsigned short)(r >> 16);
}
__device__ inline float bf2f(unsigned short h) {
    return __uint_as_float((unsigned int)h << 16);
}

// ---------------------------------------------------------------------------
// Layer 0: split x (F=3) into hi/lo bf16 padded to 32, plus row sq-norms.
__global__ void xsplit3_kernel(const float* __restrict__ x,
                               unsigned short* __restrict__ hi,
                               unsigned short* __restrict__ lo,
                               float* __restrict__ sq) {
    int row = blockIdx.x * blockDim.x + threadIdx.x;
    if (row >= BN) return;
    unsigned short hbuf[32], lbuf[32];
#pragma unroll
    for (int f = 0; f < 32; ++f) { hbuf[f] = 0; lbuf[f] = 0; }
    float s = 0.f;
#pragma unroll
    for (int f = 0; f < 3; ++f) {
        float v = x[(size_t)row * 3 + f];
        s += v * v;
        unsigned short h = f2bf(v);
        hbuf[f] = h;
        lbuf[f] = f2bf(v - bf2f(h));
    }
    sq[row] = s;
#pragma unroll
    for (int f = 0; f < 32; f += 8) {
        *(uint4*)&hi[(size_t)row * 32 + f] = *(uint4*)&hbuf[f];
        *(uint4*)&lo[(size_t)row * 32 + f] = *(uint4*)&lbuf[f];
    }
}

// ---------------------------------------------------------------------------
// Layers 1-4: fused split + sq (one x read). One wave per row.
__global__ __launch_bounds__(256) void xsplit_sq_kernel(
        const float* __restrict__ x, unsigned short* __restrict__ hi,
        unsigned short* __restrict__ lo, float* __restrict__ sq, int F) {
    int row = blockIdx.x * 4 + (threadIdx.x >> 6);
    int lane = threadIdx.x & 63;
    const float* xp = x + (size_t)row * F;
    float s = 0.f;
    for (int f = lane; f < F; f += 64) {
        float v = xp[f];
        unsigned short h = f2bf(v);
        hi[(size_t)row * F + f] = h;
        lo[(size_t)row * F + f] = f2bf(v - bf2f(h));
        s += v * v;
    }
#pragma unroll
    for (int off = 32; off > 0; off >>= 1) s += __shfl_down(s, off);
    if (lane == 0) sq[row] = s;
}

// ---------------------------------------------------------------------------
// kNN Gram GEMM: pure MFMA (bf16 hi/lo, 3 cross-phases), writes one d2 HALF
// (1024 cols) to scratch. Round-8 proven staging: 4 tiles together,
// 2 barriers/chunk, 48 MFMA per staging round.
__global__ __launch_bounds__(256) void knn_gram_kernel(
        const unsigned short* __restrict__ xh, const unsigned short* __restrict__ xl,
        const float* __restrict__ sq, float* __restrict__ d2, int F, int qbase) {
    int b = blockIdx.z;
    int row0 = blockIdx.x * 128;
    int col0 = qbase + blockIdx.y * 128;          // global col
    const unsigned short* xhb = xh + (size_t)b * NN * F;
    const unsigned short* xlb = xl + (size_t)b * NN * F;
    const float* sqb = sq + (size_t)b * NN;

    __shared__ __align__(16) unsigned short AsB[4 * 128 * 40];   // 40 KB
    unsigned short* Ah = AsB;
    unsigned short* Al = Ah + 128 * 40;
    unsigned short* Bh = Al + 128 * 40;
    unsigned short* Bl = Bh + 128 * 40;

    int tid = threadIdx.x;
    int lane = tid & 63;
    int wave = tid >> 6;
    int wr = (wave >> 1) * 64, wc = (wave & 1) * 64;
    int l15 = lane & 15, kq = lane >> 4;

    f32x4 acc[4][4];
#pragma unroll
    for (int mt = 0; mt < 4; ++mt)
#pragma unroll
        for (int nt = 0; nt < 4; ++nt) acc[mt][nt] = (f32x4){0.f, 0.f, 0.f, 0.f};

    for (int kc = 0; kc < F; kc += 32) {
        __syncthreads();
#pragma unroll
        for (int it = 0; it < 8; ++it) {
            int i = tid + it * 256;            // 0..2047
            int tile = i >> 9;                 // 512 uint4 per tile
            int rs = i & 511;
            int row = rs >> 2, sub = rs & 3;
            const unsigned short* src;
            unsigned short* dst;
            if (tile == 0)      { src = xhb + (size_t)(row0 + row) * F; dst = Ah; }
            else if (tile == 1) { src = xlb + (size_t)(row0 + row) * F; dst = Al; }
            else if (tile == 2) { src = xhb + (size_t)(col0 + row) * F; dst = Bh; }
            else                { src = xlb + (size_t)(col0 + row) * F; dst = Bl; }
            *(uint4*)&dst[row * 40 + sub * 8] = *(const uint4*)&src[kc + sub * 8];
        }
        __syncthreads();
        bf16x8 bh[4], bl[4];
#pragma unroll
        for (int t = 0; t < 4; ++t) {
            bh[t] = *(const bf16x8*)&Bh[(wc + t * 16 + l15) * 40 + kq * 8];
            bl[t] = *(const bf16x8*)&Bl[(wc + t * 16 + l15) * 40 + kq * 8];
        }
#pragma unroll
        for (int mt = 0; mt < 4; ++mt) {
            bf16x8 ah = *(const bf16x8*)&Ah[(wr + mt * 16 + l15) * 40 + kq * 8];
            bf16x8 al = *(const bf16x8*)&Al[(wr + mt * 16 + l15) * 40 + kq * 8];
#pragma unroll
            for (int nt = 0; nt < 4; ++nt) {
                acc[mt][nt] = __builtin_amdgcn_mfma_f32_16x16x32_bf16(ah, bh[nt], acc[mt][nt], 0, 0, 0);
                acc[mt][nt] = __builtin_amdgcn_mfma_f32_16x16x32_bf16(al, bh[nt], acc[mt][nt], 0, 0, 0);
                acc[mt][nt] = __builtin_amdgcn_mfma_f32_16x16x32_bf16(ah, bl[nt], acc[mt][nt], 0, 0, 0);
            }
        }
    }
#pragma unroll
    for (int mt = 0; mt < 4; ++mt) {
        int rbase = row0 + wr + mt * 16 + kq * 4;
#pragma unroll
        for (int nt = 0; nt < 4; ++nt) {
            int lc = (col0 - qbase) + wc + nt * 16 + l15;    // local half col
            float sqc = sqb[col0 + wc + nt * 16 + l15];
            f32x4 c = acc[mt][nt];
#pragma unroll
            for (int r = 0; r < 4; ++r) {
                float sqr = sqb[rbase + r];
                d2[((size_t)b * NN + rbase + r) * HC + lc] = (sqr + sqc) - 2.f * c[r];
            }
        }
    }
}

// ---------------------------------------------------------------------------
// kNN selection over the FULL row (two d2 halves), single pass, writes IDX
// directly. Block = 64 flat rows; 16 LDS-staged 64x128 chunks; thread
// (r = tid&63, p = tid>>6) scans 32 cols/chunk ascending; 4-way stable merge.
__global__ __launch_bounds__(256) void knn_select_kernel(
        const float* __restrict__ d2a, const float* __restrict__ d2b,
        int* __restrict__ idx) {
    int g0 = blockIdx.x * 64;                 // flat row base (b*NN+n)
    __shared__ __align__(16) float tile[64 * 132];   // 33792 B
    float* cd = tile;                          // overlay merge (after scans)
    int* ci = (int*)tile + 2560;

    int tid = threadIdx.x;
    int r = tid & 63;
    int p = tid >> 6;

    float bestd[KK];
    int besti[KK];
#pragma unroll
    for (int k = 0; k < KK; ++k) { bestd[k] = INFINITY; besti[k] = 0x7fffffff; }

    for (int ch = 0; ch < 16; ++ch) {
        const float* src = (ch < 8) ? d2a : d2b;
        int lc0 = (ch & 7) * 128;
        __syncthreads();   // prior scan done
#pragma unroll
        for (int it = 0; it < 8; ++it) {
            int v = tid + it * 256;            // 0..2047
            int row = v >> 5, c4 = v & 31;     // 64 rows x 32 float4
            *(float4*)&tile[row * 132 + c4 * 4] =
                *(const float4*)&src[(size_t)(g0 + row) * HC + lc0 + c4 * 4];
        }
        __syncthreads();
#pragma unroll
        for (int i = 0; i < 32; ++i) {
            int j = p * 32 + i;                // local col in chunk
            float d = tile[r * 132 + j];
            if (d < bestd[KK - 1]) {
                bestd[KK - 1] = d;
                besti[KK - 1] = ch * 128 + j;  // global col
#pragma unroll
                for (int s = KK - 1; s > 0; --s) {
                    if (bestd[s] < bestd[s - 1]) {
                        float td = bestd[s]; bestd[s] = bestd[s - 1]; bestd[s - 1] = td;
                        int ti = besti[s]; besti[s] = besti[s - 1]; besti[s - 1] = ti;
                    }
                }
            }
        }
    }
    __syncthreads();   // scans done before merge overlay
#pragma unroll
    for (int k = 0; k < KK; ++k) {
        cd[tid * KK + k] = bestd[k];
        ci[tid * KK + k] = besti[k];
    }
    __syncthreads();
    if (tid < 64) {
        int pq[4] = {0, 0, 0, 0};
        int* op = idx + (size_t)(g0 + tid) * KK;
        for (int s = 0; s < KK; ++s) {
            float bD = INFINITY; int bI = 0x7fffffff; int bq = 0;
#pragma unroll
            for (int q = 0; q < 4; ++q) {
                if (pq[q] < KK) {
                    int li = (q * 64 + tid) * KK + pq[q];
                    float d = cd[li]; int ii = ci[li];
                    if (d < bD || (d == bD && ii < bI)) { bD = d; bI = ii; bq = q; }
                }
            }
            pq[bq]++;
            op[s] = bI;
        }
    }
}

// ---------------------------------------------------------------------------
// Build WT[o'][2*fpad] bf16 with zero-padding beyond fin:
// rows o'<fout -> (W1-W2) col o', else W2 col o'-fout; k: [0,fpad)=hi, [fpad,2fpad)=lo.
__global__ void wsplit_kernel(const float* __restrict__ w, unsigned short* __restrict__ WT,
                              int fin, int fpad, int fout) {
    int i = blockIdx.x * blockDim.x + threadIdx.x;
    int total = 2 * fout * fpad;
    if (i >= total) return;
    int op = i % (2 * fout);
    int f = i / (2 * fout);
    float v = 0.f;
    if (f < fin) {
        if (op < fout) v = w[(size_t)f * fout + op] - w[(size_t)(fin + f) * fout + op];
        else v = w[(size_t)(fin + f) * fout + (op - fout)];
    }
    unsigned short h = f2bf(v);
    unsigned short l = f2bf(v - bf2f(h));
    WT[(size_t)op * (2 * fpad) + f] = h;
    WT[(size_t)op * (2 * fpad) + fpad + f] = l;
}

// ---------------------------------------------------------------------------
// MFMA GEMM (validated round 5): A|T = xsplit @ WT^T, 3-phase bf16 split.
// fin here = padded K (multiple of 32).
__global__ __launch_bounds__(256) void gemm2_mfma_kernel(
        const unsigned short* __restrict__ XSh, const unsigned short* __restrict__ XSl,
        const unsigned short* __restrict__ WT, const float* __restrict__ bias,
        float* __restrict__ Aout, float* __restrict__ Tout, int fin, int fout) {
    int m0 = blockIdx.x * 128;
    int n0 = blockIdx.y * 128;
    __shared__ __align__(16) unsigned short As[128 * 40];
    __shared__ __align__(16) unsigned short Bs[128 * 40];
    int tid = threadIdx.x;
    int lane = tid & 63;
    int wave = tid >> 6;
    int wr = (wave >> 1) * 64, wc = (wave & 1) * 64;
    int l15 = lane & 15, kq = lane >> 4;
    int w2f = 2 * fin;

    f32x4 acc[4][4];
#pragma unroll
    for (int mt = 0; mt < 4; ++mt)
#pragma unroll
        for (int nt = 0; nt < 4; ++nt) acc[mt][nt] = (f32x4){0.f, 0.f, 0.f, 0.f};

    for (int p = 0; p < 3; ++p) {
        const unsigned short* Axp = (p == 1) ? XSl : XSh;
        int bkoff = (p == 2) ? fin : 0;
        for (int kc = 0; kc < fin; kc += 32) {
            __syncthreads();
            for (int i = tid; i < 512; i += 256) {
                int row = i >> 2, sub = i & 3;
                *(uint4*)&As[row * 40 + sub * 8] =
                    *(const uint4*)&Axp[(size_t)(m0 + row) * fin + kc + sub * 8];
                *(uint4*)&Bs[row * 40 + sub * 8] =
                    *(const uint4*)&WT[(size_t)(n0 + row) * w2f + bkoff + kc + sub * 8];
            }
            __syncthreads();
            bf16x8 a[4], b[4];
#pragma unroll
            for (int t = 0; t < 4; ++t) {
                a[t] = *(const bf16x8*)&As[(wr + t * 16 + l15) * 40 + kq * 8];
                b[t] = *(const bf16x8*)&Bs[(wc + t * 16 + l15) * 40 + kq * 8];
            }
#pragma unroll
            for (int mt = 0; mt < 4; ++mt)
#pragma unroll
                for (int nt = 0; nt < 4; ++nt)
                    acc[mt][nt] = __builtin_amdgcn_mfma_f32_16x16x32_bf16(a[mt], b[nt], acc[mt][nt], 0, 0, 0);
        }
    }
#pragma unroll
    for (int mt = 0; mt < 4; ++mt) {
        int mbase = m0 + wr + mt * 16 + kq * 4;
#pragma unroll
        for (int nt = 0; nt < 4; ++nt) {
            int oc = n0 + wc + nt * 16 + l15;
            f32x4 c = acc[mt][nt];
            if (oc < fout) {
                float bv = bias[oc];
#pragma unroll
                for (int r = 0; r < 4; ++r)
                    Aout[(size_t)(mbase + r) * fout + oc] = c[r] + bv;
            } else {
                int o2 = oc - fout;
#pragma unroll
                for (int r = 0; r < 4; ++r)
                    Tout[(size_t)(mbase + r) * fout + o2] = c[r];
            }
        }
    }
}

// ---------------------------------------------------------------------------
// Grid-stride gathermax: out[e] = lrelu(A[e] + max_k T[(b*NN+idx[pn][k])*fout + o])
__global__ __launch_bounds__(256) void gathermax_kernel(
        const float* __restrict__ A, const float* __restrict__ T,
        const int* __restrict__ idx, float* __restrict__ out,
        int shift, int total) {
    int fm = (1 << shift) - 1;
    int stride = gridDim.x * 256;
    for (int e = blockIdx.x * 256 + threadIdx.x; e < total; e += stride) {
        int pn = e >> shift;
        int o = e & fm;
        int b = pn >> 11;                 // NN = 2048
        const int* ip = idx + (size_t)pn * KK;
        float m = -INFINITY;
#pragma unroll
        for (int k = 0; k < KK; ++k) {
            int j = ip[k];
            m = fmaxf(m, T[(((size_t)b << 11) + j) * (fm + 1) + o]);
        }
        float h = A[e] + m;
        out[e] = h > 0.f ? h : 0.2f * h;
    }
}

// ---------------------------------------------------------------------------
// Two-pass global max over N.
__global__ void gmax1_kernel(const float* __restrict__ h, float* __restrict__ gp) {
    int b = blockIdx.y;
    int chunk = blockIdx.z;
    int o = blockIdx.x * 256 + threadIdx.x;
    const float* hp = h + ((size_t)b * NN + chunk * 128) * 1024 + o;
    float m = -INFINITY;
    for (int n = 0; n < 128; ++n) m = fmaxf(m, hp[(size_t)n * 1024]);
    gp[((size_t)chunk * BB + b) * 1024 + o] = m;
}
__global__ void gmax2_kernel(const float* __restrict__ gp, float* __restrict__ g) {
    int b = blockIdx.y;
    int o = blockIdx.x * 256 + threadIdx.x;
    float m = -INFINITY;
    for (int c = 0; c < 16; ++c) m = fmaxf(m, gp[((size_t)c * BB + b) * 1024 + o]);
    g[(size_t)b * 1024 + o] = m;
}

// ---------------------------------------------------------------------------
__global__ __launch_bounds__(128) void mlp_kernel(const float* __restrict__ g,
                                                  const float* __restrict__ m0w, const float* __restrict__ m0b,
                                                  const float* __restrict__ m1w, const float* __restrict__ m1b,
                                                  const float* __restrict__ m2w, const float* __restrict__ m2b,
                                                  float* __restrict__ out) {
    __shared__ float gs[1024];
    __shared__ float h1[128];
    __shared__ float h2[64];
    int b = blockIdx.x, t = threadIdx.x;
    for (int i = t; i < 1024; i += 128) gs[i] = g[(size_t)b * 1024 + i];
    __syncthreads();
    float s = m0b[t];
    for (int f = 0; f < 1024; ++f) s += gs[f] * m0w[(size_t)f * 128 + t];
    h1[t] = s;
    __syncthreads();
    if (t < 64) {
        float s2 = m1b[t];
        for (int f = 0; f < 128; ++f) s2 += h1[f] * m1w[(size_t)f * 64 + t];
        h2[t] = s2;
    }
    __syncthreads();
    if (t == 0) {
        float s3 = m2b[0];
        for (int f = 0; f < 64; ++f) s3 += h2[f] * m2w[f];
        out[b] = s3;
    }
}

// ---------------------------------------------------------------------------
extern "C" void kernel_launch(void* const* d_in, const int* in_sizes, int n_in,
                              void* d_out, int out_size, void* d_ws, size_t ws_size,
                              hipStream_t stream) {
    const float* x0 = (const float*)d_in[0];
    const float* w[5], * bi[5];
    for (int i = 0; i < 5; ++i) { w[i] = (const float*)d_in[1 + 2 * i]; bi[i] = (const float*)d_in[2 + 2 * i]; }
    const float* m0w = (const float*)d_in[11]; const float* m0b = (const float*)d_in[12];
    const float* m1w = (const float*)d_in[13]; const float* m1b = (const float*)d_in[14];
    const float* m2w = (const float*)d_in[15]; const float* m2b = (const float*)d_in[16];

    float* X0 = (float*)d_ws;
    float* X1 = X0 + (size_t)BN * 1024;
    float* T  = X1 + (size_t)BN * 1024;
    float* SQ = T  + (size_t)BN * 1024;
    int*   IDX = (int*)(SQ + BN);
    float* G  = (float*)(IDX + (size_t)BN * KK);
    unsigned short* XSh = (unsigned short*)(G + (size_t)BB * 1024);
    unsigned short* XSl = XSh + (size_t)BN * 512;   // max fin = 512
    unsigned short* WT  = XSl + (size_t)BN * 512;   // max 2*1024 x 2*512 bf16

    // d2 halves: T and the dead x-buffer (nxt) each hold BN*1024 floats.
    float* GP = T;   // gmax partials (T dead after last gathermax)

    const int fouts[5] = {64, 128, 256, 512, 1024};
    const int shifts[5] = {6, 7, 8, 9, 10};
    const float* cur = x0;
    int fin = 3;
    float* bufs[2] = {X0, X1};

    for (int l = 0; l < 5; ++l) {
        int fout = fouts[l];
        float* nxt = bufs[l & 1];
        int Fg = (l == 0) ? 32 : fin;      // padded K for MFMA path

        if (l == 0) {
            xsplit3_kernel<<<(BN + 255) / 256, 256, 0, stream>>>(cur, XSh, XSl, SQ);
        } else {
            xsplit_sq_kernel<<<BN / 4, 256, 0, stream>>>(cur, XSh, XSl, SQ, fin);
        }

        // d2 halves: D2a = T, D2b = nxt (both dead until gemm2 writes them)
        float* D2a = T;
        float* D2b = nxt;
        dim3 gg2(NN / 128, HC / 128, BB);
        knn_gram_kernel<<<gg2, 256, 0, stream>>>(XSh, XSl, SQ, D2a, Fg, 0);
        knn_gram_kernel<<<gg2, 256, 0, stream>>>(XSh, XSl, SQ, D2b, Fg, HC);
        knn_select_kernel<<<BN / 64, 256, 0, stream>>>(D2a, D2b, IDX);

        int nw = 2 * fout * Fg;
        wsplit_kernel<<<(nw + 255) / 256, 256, 0, stream>>>(w[l], WT, fin, Fg, fout);
        dim3 gg(BN / 128, (2 * fout) / 128);
        gemm2_mfma_kernel<<<gg, 256, 0, stream>>>(XSh, XSl, WT, bi[l], nxt, T, Fg, fout);

        gathermax_kernel<<<2048, 256, 0, stream>>>(nxt, T, IDX, nxt, shifts[l], BN * fout);

        cur = nxt;
        fin = fout;
    }

    dim3 x1(1024 / 256, BB, 16);
    gmax1_kernel<<<x1, 256, 0, stream>>>(cur, GP);
    dim3 x2(1024 / 256, BB);
    gmax2_kernel<<<x2, 256, 0, stream>>>(GP, G);

    mlp_kernel<<<BB, 128, 0, stream>>>(G, m0w, m0b, m1w, m1b, m2w, m2b, (float*)d_out);
}

// Round 13
// 1719.316 us; speedup vs baseline: 1.4702x; 1.0476x over previous
//
#include <hip/hip_runtime.h>
#include <hip/hip_bf16.h>
#include <math.h>

#define BB 8
#define NN 2048
#define KK 10
#define BN (BB * NN)
#define HC 1024            // cols per d2 half (2 halves = full 2048)

typedef __attribute__((ext_vector_type(8))) short bf16x8;
typedef __attribute__((ext_vector_type(4))) float f32x4;

__device__ inline unsigned short f2bf(float f) {
    unsigned int u = __float_as_uint(f);
    unsigned int r = u + 0x7fffu + ((u >> 16) & 1u);
    return (unsigned short)(r >> 16);
}
__device__ inline float bf2f(unsigned short h) {
    return __uint_as_float((unsigned int)h << 16);
}

// async global->LDS DMA, 16 B/lane, dest = wave-uniform base + lane*16 [m97]
__device__ __forceinline__ void async16(const void* g, void* l) {
    __builtin_amdgcn_global_load_lds(
        (const __attribute__((address_space(1))) void*)g,
        (__attribute__((address_space(3))) void*)l, 16, 0, 0);
}

// ---------------------------------------------------------------------------
// Layer 0: split x (F=3) into hi/lo bf16 padded to 32, plus row sq-norms.
__global__ void xsplit3_kernel(const float* __restrict__ x,
                               unsigned short* __restrict__ hi,
                               unsigned short* __restrict__ lo,
                               float* __restrict__ sq) {
    int row = blockIdx.x * blockDim.x + threadIdx.x;
    if (row >= BN) return;
    unsigned short hbuf[32], lbuf[32];
#pragma unroll
    for (int f = 0; f < 32; ++f) { hbuf[f] = 0; lbuf[f] = 0; }
    float s = 0.f;
#pragma unroll
    for (int f = 0; f < 3; ++f) {
        float v = x[(size_t)row * 3 + f];
        s += v * v;
        unsigned short h = f2bf(v);
        hbuf[f] = h;
        lbuf[f] = f2bf(v - bf2f(h));
    }
    sq[row] = s;
#pragma unroll
    for (int f = 0; f < 32; f += 8) {
        *(uint4*)&hi[(size_t)row * 32 + f] = *(uint4*)&hbuf[f];
        *(uint4*)&lo[(size_t)row * 32 + f] = *(uint4*)&lbuf[f];
    }
}

// ---------------------------------------------------------------------------
// Layers 1-4: fused split + sq (one x read). One wave per row.
__global__ __launch_bounds__(256) void xsplit_sq_kernel(
        const float* __restrict__ x, unsigned short* __restrict__ hi,
        unsigned short* __restrict__ lo, float* __restrict__ sq, int F) {
    int row = blockIdx.x * 4 + (threadIdx.x >> 6);
    int lane = threadIdx.x & 63;
    const float* xp = x + (size_t)row * F;
    float s = 0.f;
    for (int f = lane; f < F; f += 64) {
        float v = xp[f];
        unsigned short h = f2bf(v);
        hi[(size_t)row * F + f] = h;
        lo[(size_t)row * F + f] = f2bf(v - bf2f(h));
        s += v * v;
    }
#pragma unroll
    for (int off = 32; off > 0; off >>= 1) s += __shfl_down(s, off);
    if (lane == 0) sq[row] = s;
}

// ---------------------------------------------------------------------------
// kNN Gram GEMM: pure MFMA (bf16 hi/lo, 3 cross-phases), writes one d2 HALF.
// Round 13: global_load_lds width-16 staging, unpadded 128x32-short tiles
// (wave-uniform dest + lane*16 — m97 pattern). LDS 32 KB.
__global__ __launch_bounds__(256) void knn_gram_kernel(
        const unsigned short* __restrict__ xh, const unsigned short* __restrict__ xl,
        const float* __restrict__ sq, float* __restrict__ d2, int F, int qbase) {
    int b = blockIdx.z;
    int row0 = blockIdx.x * 128;
    int col0 = qbase + blockIdx.y * 128;          // global col
    const unsigned short* xhb = xh + (size_t)b * NN * F;
    const unsigned short* xlb = xl + (size_t)b * NN * F;
    const float* sqb = sq + (size_t)b * NN;

    __shared__ __align__(16) unsigned short AsB[4 * 128 * 32];   // 32 KB
    unsigned short* Ah = AsB;
    unsigned short* Al = Ah + 128 * 32;
    unsigned short* Bh = Al + 128 * 32;
    unsigned short* Bl = Bh + 128 * 32;

    int tid = threadIdx.x;
    int lane = tid & 63;
    int wave = tid >> 6;
    int wr = (wave >> 1) * 64, wc = (wave & 1) * 64;
    int l15 = lane & 15, kq = lane >> 4;
    int rsub = lane >> 2;          // 0..15
    int csub = (lane & 3) * 8;     // shorts

    f32x4 acc[4][4];
#pragma unroll
    for (int mt = 0; mt < 4; ++mt)
#pragma unroll
        for (int nt = 0; nt < 4; ++nt) acc[mt][nt] = (f32x4){0.f, 0.f, 0.f, 0.f};

    for (int kc = 0; kc < F; kc += 32) {
        __syncthreads();
        // each wave DMAs rows [wave*32, wave*32+32) of each tile, 2 KB/tile
#pragma unroll
        for (int j = 0; j < 2; ++j) {
            int row = wave * 32 + j * 16 + rsub;
            int dsto = wave * 1024 + j * 512;      // shorts
            async16(xhb + (size_t)(row0 + row) * F + kc + csub, Ah + dsto);
            async16(xlb + (size_t)(row0 + row) * F + kc + csub, Al + dsto);
            async16(xhb + (size_t)(col0 + row) * F + kc + csub, Bh + dsto);
            async16(xlb + (size_t)(col0 + row) * F + kc + csub, Bl + dsto);
        }
        __syncthreads();
        bf16x8 bh[4], bl[4];
#pragma unroll
        for (int t = 0; t < 4; ++t) {
            bh[t] = *(const bf16x8*)&Bh[(wc + t * 16 + l15) * 32 + kq * 8];
            bl[t] = *(const bf16x8*)&Bl[(wc + t * 16 + l15) * 32 + kq * 8];
        }
#pragma unroll
        for (int mt = 0; mt < 4; ++mt) {
            bf16x8 ah = *(const bf16x8*)&Ah[(wr + mt * 16 + l15) * 32 + kq * 8];
            bf16x8 al = *(const bf16x8*)&Al[(wr + mt * 16 + l15) * 32 + kq * 8];
#pragma unroll
            for (int nt = 0; nt < 4; ++nt) {
                acc[mt][nt] = __builtin_amdgcn_mfma_f32_16x16x32_bf16(ah, bh[nt], acc[mt][nt], 0, 0, 0);
                acc[mt][nt] = __builtin_amdgcn_mfma_f32_16x16x32_bf16(al, bh[nt], acc[mt][nt], 0, 0, 0);
                acc[mt][nt] = __builtin_amdgcn_mfma_f32_16x16x32_bf16(ah, bl[nt], acc[mt][nt], 0, 0, 0);
            }
        }
    }
#pragma unroll
    for (int mt = 0; mt < 4; ++mt) {
        int rbase = row0 + wr + mt * 16 + kq * 4;
#pragma unroll
        for (int nt = 0; nt < 4; ++nt) {
            int lc = (col0 - qbase) + wc + nt * 16 + l15;    // local half col
            float sqc = sqb[col0 + wc + nt * 16 + l15];
            f32x4 c = acc[mt][nt];
#pragma unroll
            for (int r = 0; r < 4; ++r) {
                float sqr = sqb[rbase + r];
                d2[((size_t)b * NN + rbase + r) * HC + lc] = (sqr + sqc) - 2.f * c[r];
            }
        }
    }
}

// ---------------------------------------------------------------------------
// kNN selection over the FULL row (two d2 halves), single pass, writes IDX
// directly (validated round 12).
__global__ __launch_bounds__(256) void knn_select_kernel(
        const float* __restrict__ d2a, const float* __restrict__ d2b,
        int* __restrict__ idx) {
    int g0 = blockIdx.x * 64;                 // flat row base (b*NN+n)
    __shared__ __align__(16) float tile[64 * 132];   // 33792 B
    float* cd = tile;                          // overlay merge (after scans)
    int* ci = (int*)tile + 2560;

    int tid = threadIdx.x;
    int r = tid & 63;
    int p = tid >> 6;

    float bestd[KK];
    int besti[KK];
#pragma unroll
    for (int k = 0; k < KK; ++k) { bestd[k] = INFINITY; besti[k] = 0x7fffffff; }

    for (int ch = 0; ch < 16; ++ch) {
        const float* src = (ch < 8) ? d2a : d2b;
        int lc0 = (ch & 7) * 128;
        __syncthreads();   // prior scan done
#pragma unroll
        for (int it = 0; it < 8; ++it) {
            int v = tid + it * 256;            // 0..2047
            int row = v >> 5, c4 = v & 31;     // 64 rows x 32 float4
            *(float4*)&tile[row * 132 + c4 * 4] =
                *(const float4*)&src[(size_t)(g0 + row) * HC + lc0 + c4 * 4];
        }
        __syncthreads();
#pragma unroll
        for (int i = 0; i < 32; ++i) {
            int j = p * 32 + i;                // local col in chunk
            float d = tile[r * 132 + j];
            if (d < bestd[KK - 1]) {
                bestd[KK - 1] = d;
                besti[KK - 1] = ch * 128 + j;  // global col
#pragma unroll
                for (int s = KK - 1; s > 0; --s) {
                    if (bestd[s] < bestd[s - 1]) {
                        float td = bestd[s]; bestd[s] = bestd[s - 1]; bestd[s - 1] = td;
                        int ti = besti[s]; besti[s] = besti[s - 1]; besti[s - 1] = ti;
                    }
                }
            }
        }
    }
    __syncthreads();   // scans done before merge overlay
#pragma unroll
    for (int k = 0; k < KK; ++k) {
        cd[tid * KK + k] = bestd[k];
        ci[tid * KK + k] = besti[k];
    }
    __syncthreads();
    if (tid < 64) {
        int pq[4] = {0, 0, 0, 0};
        int* op = idx + (size_t)(g0 + tid) * KK;
        for (int s = 0; s < KK; ++s) {
            float bD = INFINITY; int bI = 0x7fffffff; int bq = 0;
#pragma unroll
            for (int q = 0; q < 4; ++q) {
                if (pq[q] < KK) {
                    int li = (q * 64 + tid) * KK + pq[q];
                    float d = cd[li]; int ii = ci[li];
                    if (d < bD || (d == bD && ii < bI)) { bD = d; bI = ii; bq = q; }
                }
            }
            pq[bq]++;
            op[s] = bI;
        }
    }
}

// ---------------------------------------------------------------------------
// Build WT[o'][2*fpad] bf16 with zero-padding beyond fin.
__global__ void wsplit_kernel(const float* __restrict__ w, unsigned short* __restrict__ WT,
                              int fin, int fpad, int fout) {
    int i = blockIdx.x * blockDim.x + threadIdx.x;
    int total = 2 * fout * fpad;
    if (i >= total) return;
    int op = i % (2 * fout);
    int f = i / (2 * fout);
    float v = 0.f;
    if (f < fin) {
        if (op < fout) v = w[(size_t)f * fout + op] - w[(size_t)(fin + f) * fout + op];
        else v = w[(size_t)(fin + f) * fout + (op - fout)];
    }
    unsigned short h = f2bf(v);
    unsigned short l = f2bf(v - bf2f(h));
    WT[(size_t)op * (2 * fpad) + f] = h;
    WT[(size_t)op * (2 * fpad) + fpad + f] = l;
}

// ---------------------------------------------------------------------------
// MFMA GEMM: A|T = xsplit @ WT^T, 3-phase bf16 split.
// Round 13: global_load_lds staging, unpadded 128x32-short tiles. LDS 16 KB.
__global__ __launch_bounds__(256) void gemm2_mfma_kernel(
        const unsigned short* __restrict__ XSh, const unsigned short* __restrict__ XSl,
        const unsigned short* __restrict__ WT, const float* __restrict__ bias,
        float* __restrict__ Aout, float* __restrict__ Tout, int fin, int fout) {
    int m0 = blockIdx.x * 128;
    int n0 = blockIdx.y * 128;
    __shared__ __align__(16) unsigned short As[128 * 32];
    __shared__ __align__(16) unsigned short Bs[128 * 32];
    int tid = threadIdx.x;
    int lane = tid & 63;
    int wave = tid >> 6;
    int wr = (wave >> 1) * 64, wc = (wave & 1) * 64;
    int l15 = lane & 15, kq = lane >> 4;
    int rsub = lane >> 2;
    int csub = (lane & 3) * 8;
    int w2f = 2 * fin;

    f32x4 acc[4][4];
#pragma unroll
    for (int mt = 0; mt < 4; ++mt)
#pragma unroll
        for (int nt = 0; nt < 4; ++nt) acc[mt][nt] = (f32x4){0.f, 0.f, 0.f, 0.f};

    for (int p = 0; p < 3; ++p) {
        const unsigned short* Axp = (p == 1) ? XSl : XSh;
        int bkoff = (p == 2) ? fin : 0;
        for (int kc = 0; kc < fin; kc += 32) {
            __syncthreads();
#pragma unroll
            for (int j = 0; j < 2; ++j) {
                int row = wave * 32 + j * 16 + rsub;
                int dsto = wave * 1024 + j * 512;
                async16(Axp + (size_t)(m0 + row) * fin + kc + csub, As + dsto);
                async16(WT + (size_t)(n0 + row) * w2f + bkoff + kc + csub, Bs + dsto);
            }
            __syncthreads();
            bf16x8 a[4], b[4];
#pragma unroll
            for (int t = 0; t < 4; ++t) {
                a[t] = *(const bf16x8*)&As[(wr + t * 16 + l15) * 32 + kq * 8];
                b[t] = *(const bf16x8*)&Bs[(wc + t * 16 + l15) * 32 + kq * 8];
            }
#pragma unroll
            for (int mt = 0; mt < 4; ++mt)
#pragma unroll
                for (int nt = 0; nt < 4; ++nt)
                    acc[mt][nt] = __builtin_amdgcn_mfma_f32_16x16x32_bf16(a[mt], b[nt], acc[mt][nt], 0, 0, 0);
        }
    }
#pragma unroll
    for (int mt = 0; mt < 4; ++mt) {
        int mbase = m0 + wr + mt * 16 + kq * 4;
#pragma unroll
        for (int nt = 0; nt < 4; ++nt) {
            int oc = n0 + wc + nt * 16 + l15;
            f32x4 c = acc[mt][nt];
            if (oc < fout) {
                float bv = bias[oc];
#pragma unroll
                for (int r = 0; r < 4; ++r)
                    Aout[(size_t)(mbase + r) * fout + oc] = c[r] + bv;
            } else {
                int o2 = oc - fout;
#pragma unroll
                for (int r = 0; r < 4; ++r)
                    Tout[(size_t)(mbase + r) * fout + o2] = c[r];
            }
        }
    }
}

// ---------------------------------------------------------------------------
// Grid-stride gathermax: out[e] = lrelu(A[e] + max_k T[(b*NN+idx[pn][k])*fout + o])
__global__ __launch_bounds__(256) void gathermax_kernel(
        const float* __restrict__ A, const float* __restrict__ T,
        const int* __restrict__ idx, float* __restrict__ out,
        int shift, int total) {
    int fm = (1 << shift) - 1;
    int stride = gridDim.x * 256;
    for (int e = blockIdx.x * 256 + threadIdx.x; e < total; e += stride) {
        int pn = e >> shift;
        int o = e & fm;
        int b = pn >> 11;                 // NN = 2048
        const int* ip = idx + (size_t)pn * KK;
        float m = -INFINITY;
#pragma unroll
        for (int k = 0; k < KK; ++k) {
            int j = ip[k];
            m = fmaxf(m, T[(((size_t)b << 11) + j) * (fm + 1) + o]);
        }
        float h = A[e] + m;
        out[e] = h > 0.f ? h : 0.2f * h;
    }
}

// ---------------------------------------------------------------------------
// Two-pass global max over N.
__global__ void gmax1_kernel(const float* __restrict__ h, float* __restrict__ gp) {
    int b = blockIdx.y;
    int chunk = blockIdx.z;
    int o = blockIdx.x * 256 + threadIdx.x;
    const float* hp = h + ((size_t)b * NN + chunk * 128) * 1024 + o;
    float m = -INFINITY;
    for (int n = 0; n < 128; ++n) m = fmaxf(m, hp[(size_t)n * 1024]);
    gp[((size_t)chunk * BB + b) * 1024 + o] = m;
}
__global__ void gmax2_kernel(const float* __restrict__ gp, float* __restrict__ g) {
    int b = blockIdx.y;
    int o = blockIdx.x * 256 + threadIdx.x;
    float m = -INFINITY;
    for (int c = 0; c < 16; ++c) m = fmaxf(m, gp[((size_t)c * BB + b) * 1024 + o]);
    g[(size_t)b * 1024 + o] = m;
}

// ---------------------------------------------------------------------------
__global__ __launch_bounds__(128) void mlp_kernel(const float* __restrict__ g,
                                                  const float* __restrict__ m0w, const float* __restrict__ m0b,
                                                  const float* __restrict__ m1w, const float* __restrict__ m1b,
                                                  const float* __restrict__ m2w, const float* __restrict__ m2b,
                                                  float* __restrict__ out) {
    __shared__ float gs[1024];
    __shared__ float h1[128];
    __shared__ float h2[64];
    int b = blockIdx.x, t = threadIdx.x;
    for (int i = t; i < 1024; i += 128) gs[i] = g[(size_t)b * 1024 + i];
    __syncthreads();
    float s = m0b[t];
    for (int f = 0; f < 1024; ++f) s += gs[f] * m0w[(size_t)f * 128 + t];
    h1[t] = s;
    __syncthreads();
    if (t < 64) {
        float s2 = m1b[t];
        for (int f = 0; f < 128; ++f) s2 += h1[f] * m1w[(size_t)f * 64 + t];
        h2[t] = s2;
    }
    __syncthreads();
    if (t == 0) {
        float s3 = m2b[0];
        for (int f = 0; f < 64; ++f) s3 += h2[f] * m2w[f];
        out[b] = s3;
    }
}

// ---------------------------------------------------------------------------
extern "C" void kernel_launch(void* const* d_in, const int* in_sizes, int n_in,
                              void* d_out, int out_size, void* d_ws, size_t ws_size,
                              hipStream_t stream) {
    const float* x0 = (const float*)d_in[0];
    const float* w[5], * bi[5];
    for (int i = 0; i < 5; ++i) { w[i] = (const float*)d_in[1 + 2 * i]; bi[i] = (const float*)d_in[2 + 2 * i]; }
    const float* m0w = (const float*)d_in[11]; const float* m0b = (const float*)d_in[12];
    const float* m1w = (const float*)d_in[13]; const float* m1b = (const float*)d_in[14];
    const float* m2w = (const float*)d_in[15]; const float* m2b = (const float*)d_in[16];

    float* X0 = (float*)d_ws;
    float* X1 = X0 + (size_t)BN * 1024;
    float* T  = X1 + (size_t)BN * 1024;
    float* SQ = T  + (size_t)BN * 1024;
    int*   IDX = (int*)(SQ + BN);
    float* G  = (float*)(IDX + (size_t)BN * KK);
    unsigned short* XSh = (unsigned short*)(G + (size_t)BB * 1024);
    unsigned short* XSl = XSh + (size_t)BN * 512;   // max fin = 512
    unsigned short* WT  = XSl + (size_t)BN * 512;   // max 2*1024 x 2*512 bf16

    float* GP = T;   // gmax partials (T dead after last gathermax)

    const int fouts[5] = {64, 128, 256, 512, 1024};
    const int shifts[5] = {6, 7, 8, 9, 10};
    const float* cur = x0;
    int fin = 3;
    float* bufs[2] = {X0, X1};

    for (int l = 0; l < 5; ++l) {
        int fout = fouts[l];
        float* nxt = bufs[l & 1];
        int Fg = (l == 0) ? 32 : fin;      // padded K for MFMA path

        if (l == 0) {
            xsplit3_kernel<<<(BN + 255) / 256, 256, 0, stream>>>(cur, XSh, XSl, SQ);
        } else {
            xsplit_sq_kernel<<<BN / 4, 256, 0, stream>>>(cur, XSh, XSl, SQ, fin);
        }

        // d2 halves: D2a = T, D2b = nxt (both dead until gemm2 writes them)
        float* D2a = T;
        float* D2b = nxt;
        dim3 gg2(NN / 128, HC / 128, BB);
        knn_gram_kernel<<<gg2, 256, 0, stream>>>(XSh, XSl, SQ, D2a, Fg, 0);
        knn_gram_kernel<<<gg2, 256, 0, stream>>>(XSh, XSl, SQ, D2b, Fg, HC);
        knn_select_kernel<<<BN / 64, 256, 0, stream>>>(D2a, D2b, IDX);

        int nw = 2 * fout * Fg;
        wsplit_kernel<<<(nw + 255) / 256, 256, 0, stream>>>(w[l], WT, fin, Fg, fout);
        dim3 gg(BN / 128, (2 * fout) / 128);
        gemm2_mfma_kernel<<<gg, 256, 0, stream>>>(XSh, XSl, WT, bi[l], nxt, T, Fg, fout);

        gathermax_kernel<<<2048, 256, 0, stream>>>(nxt, T, IDX, nxt, shifts[l], BN * fout);

        cur = nxt;
        fin = fout;
    }

    dim3 x1(1024 / 256, BB, 16);
    gmax1_kernel<<<x1, 256, 0, stream>>>(cur, GP);
    dim3 x2(1024 / 256, BB);
    gmax2_kernel<<<x2, 256, 0, stream>>>(GP, G);

    mlp_kernel<<<BB, 128, 0, stream>>>(G, m0w, m0b, m1w, m1b, m2w, m2b, (float*)d_out);
}

// Round 14
// 1683.537 us; speedup vs baseline: 1.5014x; 1.0213x over previous
//
#include <hip/hip_runtime.h>
#include <hip/hip_bf16.h>
#include <math.h>

#define BB 8
#define NN 2048
#define KK 10
#define BN (BB * NN)
#define HC 1024            // cols per d2 half (2 halves = full 2048)

typedef __attribute__((ext_vector_type(8))) short bf16x8;
typedef __attribute__((ext_vector_type(4))) float f32x4;

__device__ inline unsigned short f2bf(float f) {
    unsigned int u = __float_as_uint(f);
    unsigned int r = u + 0x7fffu + ((u >> 16) & 1u);
    return (unsigned short)(r >> 16);
}
__device__ inline float bf2f(unsigned short h) {
    return __uint_as_float((unsigned int)h << 16);
}

// async global->LDS DMA, 16 B/lane, dest = wave-uniform base + lane*16 [m97]
__device__ __forceinline__ void async16(const void* g, void* l) {
    __builtin_amdgcn_global_load_lds(
        (const __attribute__((address_space(1))) void*)g,
        (__attribute__((address_space(3))) void*)l, 16, 0, 0);
}

// ---------------------------------------------------------------------------
// Layer 0: split x (F=3) into hi/lo bf16 padded to 32, plus row sq-norms.
__global__ void xsplit3_kernel(const float* __restrict__ x,
                               unsigned short* __restrict__ hi,
                               unsigned short* __restrict__ lo,
                               float* __restrict__ sq) {
    int row = blockIdx.x * blockDim.x + threadIdx.x;
    if (row >= BN) return;
    unsigned short hbuf[32], lbuf[32];
#pragma unroll
    for (int f = 0; f < 32; ++f) { hbuf[f] = 0; lbuf[f] = 0; }
    float s = 0.f;
#pragma unroll
    for (int f = 0; f < 3; ++f) {
        float v = x[(size_t)row * 3 + f];
        s += v * v;
        unsigned short h = f2bf(v);
        hbuf[f] = h;
        lbuf[f] = f2bf(v - bf2f(h));
    }
    sq[row] = s;
#pragma unroll
    for (int f = 0; f < 32; f += 8) {
        *(uint4*)&hi[(size_t)row * 32 + f] = *(uint4*)&hbuf[f];
        *(uint4*)&lo[(size_t)row * 32 + f] = *(uint4*)&lbuf[f];
    }
}

// ---------------------------------------------------------------------------
// Layers 1-4: fused split + sq (one x read). One wave per row.
__global__ __launch_bounds__(256) void xsplit_sq_kernel(
        const float* __restrict__ x, unsigned short* __restrict__ hi,
        unsigned short* __restrict__ lo, float* __restrict__ sq, int F) {
    int row = blockIdx.x * 4 + (threadIdx.x >> 6);
    int lane = threadIdx.x & 63;
    const float* xp = x + (size_t)row * F;
    float s = 0.f;
    for (int f = lane; f < F; f += 64) {
        float v = xp[f];
        unsigned short h = f2bf(v);
        hi[(size_t)row * F + f] = h;
        lo[(size_t)row * F + f] = f2bf(v - bf2f(h));
        s += v * v;
    }
#pragma unroll
    for (int off = 32; off > 0; off >>= 1) s += __shfl_down(s, off);
    if (lane == 0) sq[row] = s;
}

// ---------------------------------------------------------------------------
// kNN Gram GEMM: pure MFMA (bf16 hi/lo, 3 cross-phases), writes one d2 HALF.
// global_load_lds width-16 staging, unpadded 128x32-short tiles (m97).
__global__ __launch_bounds__(256) void knn_gram_kernel(
        const unsigned short* __restrict__ xh, const unsigned short* __restrict__ xl,
        const float* __restrict__ sq, float* __restrict__ d2, int F, int qbase) {
    int b = blockIdx.z;
    int row0 = blockIdx.x * 128;
    int col0 = qbase + blockIdx.y * 128;          // global col
    const unsigned short* xhb = xh + (size_t)b * NN * F;
    const unsigned short* xlb = xl + (size_t)b * NN * F;
    const float* sqb = sq + (size_t)b * NN;

    __shared__ __align__(16) unsigned short AsB[4 * 128 * 32];   // 32 KB
    unsigned short* Ah = AsB;
    unsigned short* Al = Ah + 128 * 32;
    unsigned short* Bh = Al + 128 * 32;
    unsigned short* Bl = Bh + 128 * 32;

    int tid = threadIdx.x;
    int lane = tid & 63;
    int wave = tid >> 6;
    int wr = (wave >> 1) * 64, wc = (wave & 1) * 64;
    int l15 = lane & 15, kq = lane >> 4;
    int rsub = lane >> 2;          // 0..15
    int csub = (lane & 3) * 8;     // shorts

    f32x4 acc[4][4];
#pragma unroll
    for (int mt = 0; mt < 4; ++mt)
#pragma unroll
        for (int nt = 0; nt < 4; ++nt) acc[mt][nt] = (f32x4){0.f, 0.f, 0.f, 0.f};

    for (int kc = 0; kc < F; kc += 32) {
        __syncthreads();
#pragma unroll
        for (int j = 0; j < 2; ++j) {
            int row = wave * 32 + j * 16 + rsub;
            int dsto = wave * 1024 + j * 512;      // shorts
            async16(xhb + (size_t)(row0 + row) * F + kc + csub, Ah + dsto);
            async16(xlb + (size_t)(row0 + row) * F + kc + csub, Al + dsto);
            async16(xhb + (size_t)(col0 + row) * F + kc + csub, Bh + dsto);
            async16(xlb + (size_t)(col0 + row) * F + kc + csub, Bl + dsto);
        }
        __syncthreads();
        bf16x8 bh[4], bl[4];
#pragma unroll
        for (int t = 0; t < 4; ++t) {
            bh[t] = *(const bf16x8*)&Bh[(wc + t * 16 + l15) * 32 + kq * 8];
            bl[t] = *(const bf16x8*)&Bl[(wc + t * 16 + l15) * 32 + kq * 8];
        }
#pragma unroll
        for (int mt = 0; mt < 4; ++mt) {
            bf16x8 ah = *(const bf16x8*)&Ah[(wr + mt * 16 + l15) * 32 + kq * 8];
            bf16x8 al = *(const bf16x8*)&Al[(wr + mt * 16 + l15) * 32 + kq * 8];
#pragma unroll
            for (int nt = 0; nt < 4; ++nt) {
                acc[mt][nt] = __builtin_amdgcn_mfma_f32_16x16x32_bf16(ah, bh[nt], acc[mt][nt], 0, 0, 0);
                acc[mt][nt] = __builtin_amdgcn_mfma_f32_16x16x32_bf16(al, bh[nt], acc[mt][nt], 0, 0, 0);
                acc[mt][nt] = __builtin_amdgcn_mfma_f32_16x16x32_bf16(ah, bl[nt], acc[mt][nt], 0, 0, 0);
            }
        }
    }
#pragma unroll
    for (int mt = 0; mt < 4; ++mt) {
        int rbase = row0 + wr + mt * 16 + kq * 4;
#pragma unroll
        for (int nt = 0; nt < 4; ++nt) {
            int lc = (col0 - qbase) + wc + nt * 16 + l15;    // local half col
            float sqc = sqb[col0 + wc + nt * 16 + l15];
            f32x4 c = acc[mt][nt];
#pragma unroll
            for (int r = 0; r < 4; ++r) {
                float sqr = sqb[rbase + r];
                d2[((size_t)b * NN + rbase + r) * HC + lc] = (sqr + sqc) - 2.f * c[r];
            }
        }
    }
}

// ---------------------------------------------------------------------------
// kNN selection, round 14: col-split 2 (grid (BN/64, 2) = 512 blocks for TLP),
// float4 scan reads (b128, conflicts /4), writes cand[g][half][10];
// per-thread streams scan ascending cols -> stable (d,idx) merges.
__global__ __launch_bounds__(256) void knn_select_kernel(
        const float* __restrict__ d2a, const float* __restrict__ d2b,
        float* __restrict__ candD, int* __restrict__ candI) {
    int g0 = blockIdx.x * 64;                 // flat row base (b*NN+n)
    int h = blockIdx.y;                       // which d2 half
    const float* src = h ? d2b : d2a;
    int cb = h * HC;                          // global col base
    __shared__ __align__(16) float tile[64 * 132];   // 33792 B
    float* cd = tile;                          // overlay merge (after scans)
    int* ci = (int*)tile + 2560;

    int tid = threadIdx.x;
    int r = tid & 63;
    int p = tid >> 6;

    float bestd[KK];
    int besti[KK];
#pragma unroll
    for (int k = 0; k < KK; ++k) { bestd[k] = INFINITY; besti[k] = 0x7fffffff; }

    for (int ch = 0; ch < 8; ++ch) {
        __syncthreads();   // prior scan done
#pragma unroll
        for (int it = 0; it < 8; ++it) {
            int v = tid + it * 256;            // 0..2047
            int row = v >> 5, c4 = v & 31;     // 64 rows x 32 float4
            *(float4*)&tile[row * 132 + c4 * 4] =
                *(const float4*)&src[(size_t)(g0 + row) * HC + ch * 128 + c4 * 4];
        }
        __syncthreads();
#pragma unroll
        for (int i = 0; i < 8; ++i) {
            float4 v4 = *(const float4*)&tile[r * 132 + p * 32 + i * 4];
            float dv[4] = {v4.x, v4.y, v4.z, v4.w};
#pragma unroll
            for (int s4 = 0; s4 < 4; ++s4) {
                float d = dv[s4];
                if (d < bestd[KK - 1]) {
                    bestd[KK - 1] = d;
                    besti[KK - 1] = cb + ch * 128 + p * 32 + i * 4 + s4;
#pragma unroll
                    for (int s = KK - 1; s > 0; --s) {
                        if (bestd[s] < bestd[s - 1]) {
                            float td = bestd[s]; bestd[s] = bestd[s - 1]; bestd[s - 1] = td;
                            int ti = besti[s]; besti[s] = besti[s - 1]; besti[s - 1] = ti;
                        }
                    }
                }
            }
        }
    }
    __syncthreads();   // scans done before merge overlay
#pragma unroll
    for (int k = 0; k < KK; ++k) {
        cd[tid * KK + k] = bestd[k];
        ci[tid * KK + k] = besti[k];
    }
    __syncthreads();
    if (tid < 64) {
        int pq[4] = {0, 0, 0, 0};
        size_t base = ((size_t)(g0 + tid) * 2 + h) * KK;
        for (int s = 0; s < KK; ++s) {
            float bD = INFINITY; int bI = 0x7fffffff; int bq = 0;
#pragma unroll
            for (int q = 0; q < 4; ++q) {
                if (pq[q] < KK) {
                    int li = (q * 64 + tid) * KK + pq[q];
                    float d = cd[li]; int ii = ci[li];
                    if (d < bD || (d == bD && ii < bI)) { bD = d; bI = ii; bq = q; }
                }
            }
            pq[bq]++;
            candD[base + s] = bD;
            candI[base + s] = bI;
        }
    }
}

// ---------------------------------------------------------------------------
// merge 2 sorted 10-lists per row -> final top-10 indices
__global__ void knn_merge_kernel(const float* __restrict__ candD,
                                 const int* __restrict__ candI,
                                 int* __restrict__ idx) {
    int g = blockIdx.x * blockDim.x + threadIdx.x;
    if (g >= BN) return;
    size_t base = (size_t)g * 2 * KK;
    int p0 = 0, p1 = 0;
    int* op = idx + (size_t)g * KK;
    for (int s = 0; s < KK; ++s) {
        float d0 = candD[base + p0];
        int i0 = candI[base + p0];
        float d1 = candD[base + KK + p1];
        int i1 = candI[base + KK + p1];
        if (d0 < d1 || (d0 == d1 && i0 < i1)) { op[s] = i0; p0++; }
        else { op[s] = i1; p1++; }
    }
}

// ---------------------------------------------------------------------------
// Build WT[o'][2*fpad] bf16 with zero-padding beyond fin.
__global__ void wsplit_kernel(const float* __restrict__ w, unsigned short* __restrict__ WT,
                              int fin, int fpad, int fout) {
    int i = blockIdx.x * blockDim.x + threadIdx.x;
    int total = 2 * fout * fpad;
    if (i >= total) return;
    int op = i % (2 * fout);
    int f = i / (2 * fout);
    float v = 0.f;
    if (f < fin) {
        if (op < fout) v = w[(size_t)f * fout + op] - w[(size_t)(fin + f) * fout + op];
        else v = w[(size_t)(fin + f) * fout + (op - fout)];
    }
    unsigned short h = f2bf(v);
    unsigned short l = f2bf(v - bf2f(h));
    WT[(size_t)op * (2 * fpad) + f] = h;
    WT[(size_t)op * (2 * fpad) + fpad + f] = l;
}

// ---------------------------------------------------------------------------
// MFMA GEMM: A|T = xsplit @ WT^T, 3-phase bf16 split, async16 staging.
__global__ __launch_bounds__(256) void gemm2_mfma_kernel(
        const unsigned short* __restrict__ XSh, const unsigned short* __restrict__ XSl,
        const unsigned short* __restrict__ WT, const float* __restrict__ bias,
        float* __restrict__ Aout, float* __restrict__ Tout, int fin, int fout) {
    int m0 = blockIdx.x * 128;
    int n0 = blockIdx.y * 128;
    __shared__ __align__(16) unsigned short As[128 * 32];
    __shared__ __align__(16) unsigned short Bs[128 * 32];
    int tid = threadIdx.x;
    int lane = tid & 63;
    int wave = tid >> 6;
    int wr = (wave >> 1) * 64, wc = (wave & 1) * 64;
    int l15 = lane & 15, kq = lane >> 4;
    int rsub = lane >> 2;
    int csub = (lane & 3) * 8;
    int w2f = 2 * fin;

    f32x4 acc[4][4];
#pragma unroll
    for (int mt = 0; mt < 4; ++mt)
#pragma unroll
        for (int nt = 0; nt < 4; ++nt) acc[mt][nt] = (f32x4){0.f, 0.f, 0.f, 0.f};

    for (int p = 0; p < 3; ++p) {
        const unsigned short* Axp = (p == 1) ? XSl : XSh;
        int bkoff = (p == 2) ? fin : 0;
        for (int kc = 0; kc < fin; kc += 32) {
            __syncthreads();
#pragma unroll
            for (int j = 0; j < 2; ++j) {
                int row = wave * 32 + j * 16 + rsub;
                int dsto = wave * 1024 + j * 512;
                async16(Axp + (size_t)(m0 + row) * fin + kc + csub, As + dsto);
                async16(WT + (size_t)(n0 + row) * w2f + bkoff + kc + csub, Bs + dsto);
            }
            __syncthreads();
            bf16x8 a[4], b[4];
#pragma unroll
            for (int t = 0; t < 4; ++t) {
                a[t] = *(const bf16x8*)&As[(wr + t * 16 + l15) * 32 + kq * 8];
                b[t] = *(const bf16x8*)&Bs[(wc + t * 16 + l15) * 32 + kq * 8];
            }
#pragma unroll
            for (int mt = 0; mt < 4; ++mt)
#pragma unroll
                for (int nt = 0; nt < 4; ++nt)
                    acc[mt][nt] = __builtin_amdgcn_mfma_f32_16x16x32_bf16(a[mt], b[nt], acc[mt][nt], 0, 0, 0);
        }
    }
#pragma unroll
    for (int mt = 0; mt < 4; ++mt) {
        int mbase = m0 + wr + mt * 16 + kq * 4;
#pragma unroll
        for (int nt = 0; nt < 4; ++nt) {
            int oc = n0 + wc + nt * 16 + l15;
            f32x4 c = acc[mt][nt];
            if (oc < fout) {
                float bv = bias[oc];
#pragma unroll
                for (int r = 0; r < 4; ++r)
                    Aout[(size_t)(mbase + r) * fout + oc] = c[r] + bv;
            } else {
                int o2 = oc - fout;
#pragma unroll
                for (int r = 0; r < 4; ++r)
                    Tout[(size_t)(mbase + r) * fout + o2] = c[r];
            }
        }
    }
}

// ---------------------------------------------------------------------------
// Grid-stride gathermax: out[e] = lrelu(A[e] + max_k T[(b*NN+idx[pn][k])*fout + o])
__global__ __launch_bounds__(256) void gathermax_kernel(
        const float* __restrict__ A, const float* __restrict__ T,
        const int* __restrict__ idx, float* __restrict__ out,
        int shift, int total) {
    int fm = (1 << shift) - 1;
    int stride = gridDim.x * 256;
    for (int e = blockIdx.x * 256 + threadIdx.x; e < total; e += stride) {
        int pn = e >> shift;
        int o = e & fm;
        int b = pn >> 11;                 // NN = 2048
        const int* ip = idx + (size_t)pn * KK;
        float m = -INFINITY;
#pragma unroll
        for (int k = 0; k < KK; ++k) {
            int j = ip[k];
            m = fmaxf(m, T[(((size_t)b << 11) + j) * (fm + 1) + o]);
        }
        float h = A[e] + m;
        out[e] = h > 0.f ? h : 0.2f * h;
    }
}

// ---------------------------------------------------------------------------
// Two-pass global max over N.
__global__ void gmax1_kernel(const float* __restrict__ h, float* __restrict__ gp) {
    int b = blockIdx.y;
    int chunk = blockIdx.z;
    int o = blockIdx.x * 256 + threadIdx.x;
    const float* hp = h + ((size_t)b * NN + chunk * 128) * 1024 + o;
    float m = -INFINITY;
    for (int n = 0; n < 128; ++n) m = fmaxf(m, hp[(size_t)n * 1024]);
    gp[((size_t)chunk * BB + b) * 1024 + o] = m;
}
__global__ void gmax2_kernel(const float* __restrict__ gp, float* __restrict__ g) {
    int b = blockIdx.y;
    int o = blockIdx.x * 256 + threadIdx.x;
    float m = -INFINITY;
    for (int c = 0; c < 16; ++c) m = fmaxf(m, gp[((size_t)c * BB + b) * 1024 + o]);
    g[(size_t)b * 1024 + o] = m;
}

// ---------------------------------------------------------------------------
__global__ __launch_bounds__(128) void mlp_kernel(const float* __restrict__ g,
                                                  const float* __restrict__ m0w, const float* __restrict__ m0b,
                                                  const float* __restrict__ m1w, const float* __restrict__ m1b,
                                                  const float* __restrict__ m2w, const float* __restrict__ m2b,
                                                  float* __restrict__ out) {
    __shared__ float gs[1024];
    __shared__ float h1[128];
    __shared__ float h2[64];
    int b = blockIdx.x, t = threadIdx.x;
    for (int i = t; i < 1024; i += 128) gs[i] = g[(size_t)b * 1024 + i];
    __syncthreads();
    float s = m0b[t];
    for (int f = 0; f < 1024; ++f) s += gs[f] * m0w[(size_t)f * 128 + t];
    h1[t] = s;
    __syncthreads();
    if (t < 64) {
        float s2 = m1b[t];
        for (int f = 0; f < 128; ++f) s2 += h1[f] * m1w[(size_t)f * 64 + t];
        h2[t] = s2;
    }
    __syncthreads();
    if (t == 0) {
        float s3 = m2b[0];
        for (int f = 0; f < 64; ++f) s3 += h2[f] * m2w[f];
        out[b] = s3;
    }
}

// ---------------------------------------------------------------------------
extern "C" void kernel_launch(void* const* d_in, const int* in_sizes, int n_in,
                              void* d_out, int out_size, void* d_ws, size_t ws_size,
                              hipStream_t stream) {
    const float* x0 = (const float*)d_in[0];
    const float* w[5], * bi[5];
    for (int i = 0; i < 5; ++i) { w[i] = (const float*)d_in[1 + 2 * i]; bi[i] = (const float*)d_in[2 + 2 * i]; }
    const float* m0w = (const float*)d_in[11]; const float* m0b = (const float*)d_in[12];
    const float* m1w = (const float*)d_in[13]; const float* m1b = (const float*)d_in[14];
    const float* m2w = (const float*)d_in[15]; const float* m2b = (const float*)d_in[16];

    float* X0 = (float*)d_ws;
    float* X1 = X0 + (size_t)BN * 1024;
    float* T  = X1 + (size_t)BN * 1024;
    float* SQ = T  + (size_t)BN * 1024;
    int*   IDX = (int*)(SQ + BN);
    float* G  = (float*)(IDX + (size_t)BN * KK);
    unsigned short* XSh = (unsigned short*)(G + (size_t)BB * 1024);
    unsigned short* XSl = XSh + (size_t)BN * 512;   // max fin = 512
    unsigned short* WT  = XSl + (size_t)BN * 512;   // max 2*1024 x 2*512 bf16
    float* candD = (float*)(WT + (size_t)2 * 1024 * 1024);   // BN*2*KK floats
    int*   candI = (int*)(candD + (size_t)BN * 2 * KK);      // BN*2*KK ints

    float* GP = T;   // gmax partials (T dead after last gathermax)

    const int fouts[5] = {64, 128, 256, 512, 1024};
    const int shifts[5] = {6, 7, 8, 9, 10};
    const float* cur = x0;
    int fin = 3;
    float* bufs[2] = {X0, X1};

    for (int l = 0; l < 5; ++l) {
        int fout = fouts[l];
        float* nxt = bufs[l & 1];
        int Fg = (l == 0) ? 32 : fin;      // padded K for MFMA path

        if (l == 0) {
            xsplit3_kernel<<<(BN + 255) / 256, 256, 0, stream>>>(cur, XSh, XSl, SQ);
        } else {
            xsplit_sq_kernel<<<BN / 4, 256, 0, stream>>>(cur, XSh, XSl, SQ, fin);
        }

        // d2 halves: D2a = T, D2b = nxt (both dead until gemm2 writes them)
        float* D2a = T;
        float* D2b = nxt;
        dim3 gg2(NN / 128, HC / 128, BB);
        knn_gram_kernel<<<gg2, 256, 0, stream>>>(XSh, XSl, SQ, D2a, Fg, 0);
        knn_gram_kernel<<<gg2, 256, 0, stream>>>(XSh, XSl, SQ, D2b, Fg, HC);
        dim3 sg(BN / 64, 2);
        knn_select_kernel<<<sg, 256, 0, stream>>>(D2a, D2b, candD, candI);
        knn_merge_kernel<<<(BN + 255) / 256, 256, 0, stream>>>(candD, candI, IDX);

        int nw = 2 * fout * Fg;
        wsplit_kernel<<<(nw + 255) / 256, 256, 0, stream>>>(w[l], WT, fin, Fg, fout);
        dim3 gg(BN / 128, (2 * fout) / 128);
        gemm2_mfma_kernel<<<gg, 256, 0, stream>>>(XSh, XSl, WT, bi[l], nxt, T, Fg, fout);

        gathermax_kernel<<<2048, 256, 0, stream>>>(nxt, T, IDX, nxt, shifts[l], BN * fout);

        cur = nxt;
        fin = fout;
    }

    dim3 x1(1024 / 256, BB, 16);
    gmax1_kernel<<<x1, 256, 0, stream>>>(cur, GP);
    dim3 x2(1024 / 256, BB);
    gmax2_kernel<<<x2, 256, 0, stream>>>(GP, G);

    mlp_kernel<<<BB, 128, 0, stream>>>(G, m0w, m0b, m1w, m1b, m2w, m2b, (float*)d_out);
}

// Round 15
// 1136.336 us; speedup vs baseline: 2.2245x; 1.4815x over previous
//
#include <hip/hip_runtime.h>
#include <hip/hip_bf16.h>
#include <math.h>

#define BB 8
#define NN 2048
#define KK 10
#define BN (BB * NN)
#define HC 1024            // cols per d2 half (2 halves = full 2048)

typedef __attribute__((ext_vector_type(8))) short bf16x8;
typedef __attribute__((ext_vector_type(4))) float f32x4;

__device__ inline unsigned short f2bf(float f) {
    unsigned int u = __float_as_uint(f);
    unsigned int r = u + 0x7fffu + ((u >> 16) & 1u);
    return (unsigned short)(r >> 16);
}
__device__ inline float bf2f(unsigned short h) {
    return __uint_as_float((unsigned int)h << 16);
}

// async global->LDS DMA, 16 B/lane, dest = wave-uniform base + lane*16 [m97]
__device__ __forceinline__ void async16(const void* g, void* l) {
    __builtin_amdgcn_global_load_lds(
        (const __attribute__((address_space(1))) void*)g,
        (__attribute__((address_space(3))) void*)l, 16, 0, 0);
}

// ---------------------------------------------------------------------------
// Layer 0: split x (F=3) into hi/lo bf16 padded to 32, plus row sq-norms.
__global__ void xsplit3_kernel(const float* __restrict__ x,
                               unsigned short* __restrict__ hi,
                               unsigned short* __restrict__ lo,
                               float* __restrict__ sq) {
    int row = blockIdx.x * blockDim.x + threadIdx.x;
    if (row >= BN) return;
    unsigned short hbuf[32], lbuf[32];
#pragma unroll
    for (int f = 0; f < 32; ++f) { hbuf[f] = 0; lbuf[f] = 0; }
    float s = 0.f;
#pragma unroll
    for (int f = 0; f < 3; ++f) {
        float v = x[(size_t)row * 3 + f];
        s += v * v;
        unsigned short h = f2bf(v);
        hbuf[f] = h;
        lbuf[f] = f2bf(v - bf2f(h));
    }
    sq[row] = s;
#pragma unroll
    for (int f = 0; f < 32; f += 8) {
        *(uint4*)&hi[(size_t)row * 32 + f] = *(uint4*)&hbuf[f];
        *(uint4*)&lo[(size_t)row * 32 + f] = *(uint4*)&lbuf[f];
    }
}

// ---------------------------------------------------------------------------
// Layers 1-4: fused split + sq (one x read). One wave per row.
__global__ __launch_bounds__(256) void xsplit_sq_kernel(
        const float* __restrict__ x, unsigned short* __restrict__ hi,
        unsigned short* __restrict__ lo, float* __restrict__ sq, int F) {
    int row = blockIdx.x * 4 + (threadIdx.x >> 6);
    int lane = threadIdx.x & 63;
    const float* xp = x + (size_t)row * F;
    float s = 0.f;
    for (int f = lane; f < F; f += 64) {
        float v = xp[f];
        unsigned short h = f2bf(v);
        hi[(size_t)row * F + f] = h;
        lo[(size_t)row * F + f] = f2bf(v - bf2f(h));
        s += v * v;
    }
#pragma unroll
    for (int off = 32; off > 0; off >>= 1) s += __shfl_down(s, off);
    if (lane == 0) sq[row] = s;
}

// ---------------------------------------------------------------------------
// kNN Gram GEMM: pure MFMA (bf16 hi/lo, 3 cross-phases), writes one d2 HALF.
// global_load_lds width-16 staging, unpadded 128x32-short tiles (m97).
__global__ __launch_bounds__(256) void knn_gram_kernel(
        const unsigned short* __restrict__ xh, const unsigned short* __restrict__ xl,
        const float* __restrict__ sq, float* __restrict__ d2, int F, int qbase) {
    int b = blockIdx.z;
    int row0 = blockIdx.x * 128;
    int col0 = qbase + blockIdx.y * 128;          // global col
    const unsigned short* xhb = xh + (size_t)b * NN * F;
    const unsigned short* xlb = xl + (size_t)b * NN * F;
    const float* sqb = sq + (size_t)b * NN;

    __shared__ __align__(16) unsigned short AsB[4 * 128 * 32];   // 32 KB
    unsigned short* Ah = AsB;
    unsigned short* Al = Ah + 128 * 32;
    unsigned short* Bh = Al + 128 * 32;
    unsigned short* Bl = Bh + 128 * 32;

    int tid = threadIdx.x;
    int lane = tid & 63;
    int wave = tid >> 6;
    int wr = (wave >> 1) * 64, wc = (wave & 1) * 64;
    int l15 = lane & 15, kq = lane >> 4;
    int rsub = lane >> 2;          // 0..15
    int csub = (lane & 3) * 8;     // shorts

    f32x4 acc[4][4];
#pragma unroll
    for (int mt = 0; mt < 4; ++mt)
#pragma unroll
        for (int nt = 0; nt < 4; ++nt) acc[mt][nt] = (f32x4){0.f, 0.f, 0.f, 0.f};

    for (int kc = 0; kc < F; kc += 32) {
        __syncthreads();
#pragma unroll
        for (int j = 0; j < 2; ++j) {
            int row = wave * 32 + j * 16 + rsub;
            int dsto = wave * 1024 + j * 512;      // shorts
            async16(xhb + (size_t)(row0 + row) * F + kc + csub, Ah + dsto);
            async16(xlb + (size_t)(row0 + row) * F + kc + csub, Al + dsto);
            async16(xhb + (size_t)(col0 + row) * F + kc + csub, Bh + dsto);
            async16(xlb + (size_t)(col0 + row) * F + kc + csub, Bl + dsto);
        }
        __syncthreads();
        bf16x8 bh[4], bl[4];
#pragma unroll
        for (int t = 0; t < 4; ++t) {
            bh[t] = *(const bf16x8*)&Bh[(wc + t * 16 + l15) * 32 + kq * 8];
            bl[t] = *(const bf16x8*)&Bl[(wc + t * 16 + l15) * 32 + kq * 8];
        }
#pragma unroll
        for (int mt = 0; mt < 4; ++mt) {
            bf16x8 ah = *(const bf16x8*)&Ah[(wr + mt * 16 + l15) * 32 + kq * 8];
            bf16x8 al = *(const bf16x8*)&Al[(wr + mt * 16 + l15) * 32 + kq * 8];
#pragma unroll
            for (int nt = 0; nt < 4; ++nt) {
                acc[mt][nt] = __builtin_amdgcn_mfma_f32_16x16x32_bf16(ah, bh[nt], acc[mt][nt], 0, 0, 0);
                acc[mt][nt] = __builtin_amdgcn_mfma_f32_16x16x32_bf16(al, bh[nt], acc[mt][nt], 0, 0, 0);
                acc[mt][nt] = __builtin_amdgcn_mfma_f32_16x16x32_bf16(ah, bl[nt], acc[mt][nt], 0, 0, 0);
            }
        }
    }
#pragma unroll
    for (int mt = 0; mt < 4; ++mt) {
        int rbase = row0 + wr + mt * 16 + kq * 4;
#pragma unroll
        for (int nt = 0; nt < 4; ++nt) {
            int lc = (col0 - qbase) + wc + nt * 16 + l15;    // local half col
            float sqc = sqb[col0 + wc + nt * 16 + l15];
            f32x4 c = acc[mt][nt];
#pragma unroll
            for (int r = 0; r < 4; ++r) {
                float sqr = sqb[rbase + r];
                d2[((size_t)b * NN + rbase + r) * HC + lc] = (sqr + sqc) - 2.f * c[r];
            }
        }
    }
}

// ---------------------------------------------------------------------------
// kNN selection, round 15: WAVE-PER-ROW, no LDS, no barriers.
// Lane reads float4 at col = it*256 + lane*4 over both halves (32 cands),
// keeps stable lane-local top-10, then 10 rounds of 64-lane butterfly
// arg-min over (d, idx) lexicographic; round-s winner parks in lane s.
__global__ __launch_bounds__(256) void knn_select_kernel(
        const float* __restrict__ d2a, const float* __restrict__ d2b,
        int* __restrict__ idx) {
    int row = blockIdx.x * 4 + (threadIdx.x >> 6);   // flat row (b*NN+n)
    int lane = threadIdx.x & 63;
    const float* ra = d2a + (size_t)row * HC;
    const float* rb = d2b + (size_t)row * HC;

    float4 v[8];
#pragma unroll
    for (int it = 0; it < 4; ++it) {
        v[it]     = *(const float4*)&ra[it * 256 + lane * 4];
        v[it + 4] = *(const float4*)&rb[it * 256 + lane * 4];
    }

    float bestd[KK];
    int besti[KK];
#pragma unroll
    for (int k = 0; k < KK; ++k) { bestd[k] = INFINITY; besti[k] = 0x7fffffff; }

#pragma unroll
    for (int it = 0; it < 8; ++it) {
        int cbase = ((it < 4) ? (it * 256) : (HC + (it - 4) * 256)) + lane * 4;
        float dv[4] = {v[it].x, v[it].y, v[it].z, v[it].w};
#pragma unroll
        for (int s4 = 0; s4 < 4; ++s4) {
            float d = dv[s4];
            if (d < bestd[KK - 1]) {           // strict: idx-stable (asc col/lane)
                bestd[KK - 1] = d;
                besti[KK - 1] = cbase + s4;
#pragma unroll
                for (int s = KK - 1; s > 0; --s) {
                    if (bestd[s] < bestd[s - 1]) {
                        float td = bestd[s]; bestd[s] = bestd[s - 1]; bestd[s - 1] = td;
                        int ti = besti[s]; besti[s] = besti[s - 1]; besti[s - 1] = ti;
                    }
                }
            }
        }
    }

    // 10 rounds of wave arg-min merge (lex (d, idx)); winner lane advances.
    int h = 0;
    int mywin = 0;
    for (int s = 0; s < KK; ++s) {
        float dd = (h < KK) ? bestd[h] : INFINITY;
        int ii = (h < KK) ? besti[h] : 0x7fffffff;
        float d0 = dd; int i0 = ii;
#pragma unroll
        for (int off = 32; off > 0; off >>= 1) {
            float od = __shfl_xor(dd, off);
            int oi = __shfl_xor(ii, off);
            if (od < dd || (od == dd && oi < ii)) { dd = od; ii = oi; }
        }
        if (lane == s) mywin = ii;
        if (h < KK && i0 == ii && d0 == dd) h++;   // idx unique -> exactly one lane
    }
    if (lane < KK) idx[(size_t)row * KK + lane] = mywin;
}

// ---------------------------------------------------------------------------
// Build WT[o'][2*fpad] bf16 with zero-padding beyond fin.
__global__ void wsplit_kernel(const float* __restrict__ w, unsigned short* __restrict__ WT,
                              int fin, int fpad, int fout) {
    int i = blockIdx.x * blockDim.x + threadIdx.x;
    int total = 2 * fout * fpad;
    if (i >= total) return;
    int op = i % (2 * fout);
    int f = i / (2 * fout);
    float v = 0.f;
    if (f < fin) {
        if (op < fout) v = w[(size_t)f * fout + op] - w[(size_t)(fin + f) * fout + op];
        else v = w[(size_t)(fin + f) * fout + (op - fout)];
    }
    unsigned short h = f2bf(v);
    unsigned short l = f2bf(v - bf2f(h));
    WT[(size_t)op * (2 * fpad) + f] = h;
    WT[(size_t)op * (2 * fpad) + fpad + f] = l;
}

// ---------------------------------------------------------------------------
// MFMA GEMM: A|T = xsplit @ WT^T, 3-phase bf16 split, async16 staging.
__global__ __launch_bounds__(256) void gemm2_mfma_kernel(
        const unsigned short* __restrict__ XSh, const unsigned short* __restrict__ XSl,
        const unsigned short* __restrict__ WT, const float* __restrict__ bias,
        float* __restrict__ Aout, float* __restrict__ Tout, int fin, int fout) {
    int m0 = blockIdx.x * 128;
    int n0 = blockIdx.y * 128;
    __shared__ __align__(16) unsigned short As[128 * 32];
    __shared__ __align__(16) unsigned short Bs[128 * 32];
    int tid = threadIdx.x;
    int lane = tid & 63;
    int wave = tid >> 6;
    int wr = (wave >> 1) * 64, wc = (wave & 1) * 64;
    int l15 = lane & 15, kq = lane >> 4;
    int rsub = lane >> 2;
    int csub = (lane & 3) * 8;
    int w2f = 2 * fin;

    f32x4 acc[4][4];
#pragma unroll
    for (int mt = 0; mt < 4; ++mt)
#pragma unroll
        for (int nt = 0; nt < 4; ++nt) acc[mt][nt] = (f32x4){0.f, 0.f, 0.f, 0.f};

    for (int p = 0; p < 3; ++p) {
        const unsigned short* Axp = (p == 1) ? XSl : XSh;
        int bkoff = (p == 2) ? fin : 0;
        for (int kc = 0; kc < fin; kc += 32) {
            __syncthreads();
#pragma unroll
            for (int j = 0; j < 2; ++j) {
                int row = wave * 32 + j * 16 + rsub;
                int dsto = wave * 1024 + j * 512;
                async16(Axp + (size_t)(m0 + row) * fin + kc + csub, As + dsto);
                async16(WT + (size_t)(n0 + row) * w2f + bkoff + kc + csub, Bs + dsto);
            }
            __syncthreads();
            bf16x8 a[4], b[4];
#pragma unroll
            for (int t = 0; t < 4; ++t) {
                a[t] = *(const bf16x8*)&As[(wr + t * 16 + l15) * 32 + kq * 8];
                b[t] = *(const bf16x8*)&Bs[(wc + t * 16 + l15) * 32 + kq * 8];
            }
#pragma unroll
            for (int mt = 0; mt < 4; ++mt)
#pragma unroll
                for (int nt = 0; nt < 4; ++nt)
                    acc[mt][nt] = __builtin_amdgcn_mfma_f32_16x16x32_bf16(a[mt], b[nt], acc[mt][nt], 0, 0, 0);
        }
    }
#pragma unroll
    for (int mt = 0; mt < 4; ++mt) {
        int mbase = m0 + wr + mt * 16 + kq * 4;
#pragma unroll
        for (int nt = 0; nt < 4; ++nt) {
            int oc = n0 + wc + nt * 16 + l15;
            f32x4 c = acc[mt][nt];
            if (oc < fout) {
                float bv = bias[oc];
#pragma unroll
                for (int r = 0; r < 4; ++r)
                    Aout[(size_t)(mbase + r) * fout + oc] = c[r] + bv;
            } else {
                int o2 = oc - fout;
#pragma unroll
                for (int r = 0; r < 4; ++r)
                    Tout[(size_t)(mbase + r) * fout + o2] = c[r];
            }
        }
    }
}

// ---------------------------------------------------------------------------
// Grid-stride gathermax: out[e] = lrelu(A[e] + max_k T[(b*NN+idx[pn][k])*fout + o])
__global__ __launch_bounds__(256) void gathermax_kernel(
        const float* __restrict__ A, const float* __restrict__ T,
        const int* __restrict__ idx, float* __restrict__ out,
        int shift, int total) {
    int fm = (1 << shift) - 1;
    int stride = gridDim.x * 256;
    for (int e = blockIdx.x * 256 + threadIdx.x; e < total; e += stride) {
        int pn = e >> shift;
        int o = e & fm;
        int b = pn >> 11;                 // NN = 2048
        const int* ip = idx + (size_t)pn * KK;
        float m = -INFINITY;
#pragma unroll
        for (int k = 0; k < KK; ++k) {
            int j = ip[k];
            m = fmaxf(m, T[(((size_t)b << 11) + j) * (fm + 1) + o]);
        }
        float h = A[e] + m;
        out[e] = h > 0.f ? h : 0.2f * h;
    }
}

// ---------------------------------------------------------------------------
// Two-pass global max over N.
__global__ void gmax1_kernel(const float* __restrict__ h, float* __restrict__ gp) {
    int b = blockIdx.y;
    int chunk = blockIdx.z;
    int o = blockIdx.x * 256 + threadIdx.x;
    const float* hp = h + ((size_t)b * NN + chunk * 128) * 1024 + o;
    float m = -INFINITY;
    for (int n = 0; n < 128; ++n) m = fmaxf(m, hp[(size_t)n * 1024]);
    gp[((size_t)chunk * BB + b) * 1024 + o] = m;
}
__global__ void gmax2_kernel(const float* __restrict__ gp, float* __restrict__ g) {
    int b = blockIdx.y;
    int o = blockIdx.x * 256 + threadIdx.x;
    float m = -INFINITY;
    for (int c = 0; c < 16; ++c) m = fmaxf(m, gp[((size_t)c * BB + b) * 1024 + o]);
    g[(size_t)b * 1024 + o] = m;
}

// ---------------------------------------------------------------------------
__global__ __launch_bounds__(128) void mlp_kernel(const float* __restrict__ g,
                                                  const float* __restrict__ m0w, const float* __restrict__ m0b,
                                                  const float* __restrict__ m1w, const float* __restrict__ m1b,
                                                  const float* __restrict__ m2w, const float* __restrict__ m2b,
                                                  float* __restrict__ out) {
    __shared__ float gs[1024];
    __shared__ float h1[128];
    __shared__ float h2[64];
    int b = blockIdx.x, t = threadIdx.x;
    for (int i = t; i < 1024; i += 128) gs[i] = g[(size_t)b * 1024 + i];
    __syncthreads();
    float s = m0b[t];
    for (int f = 0; f < 1024; ++f) s += gs[f] * m0w[(size_t)f * 128 + t];
    h1[t] = s;
    __syncthreads();
    if (t < 64) {
        float s2 = m1b[t];
        for (int f = 0; f < 128; ++f) s2 += h1[f] * m1w[(size_t)f * 64 + t];
        h2[t] = s2;
    }
    __syncthreads();
    if (t == 0) {
        float s3 = m2b[0];
        for (int f = 0; f < 64; ++f) s3 += h2[f] * m2w[f];
        out[b] = s3;
    }
}

// ---------------------------------------------------------------------------
extern "C" void kernel_launch(void* const* d_in, const int* in_sizes, int n_in,
                              void* d_out, int out_size, void* d_ws, size_t ws_size,
                              hipStream_t stream) {
    const float* x0 = (const float*)d_in[0];
    const float* w[5], * bi[5];
    for (int i = 0; i < 5; ++i) { w[i] = (const float*)d_in[1 + 2 * i]; bi[i] = (const float*)d_in[2 + 2 * i]; }
    const float* m0w = (const float*)d_in[11]; const float* m0b = (const float*)d_in[12];
    const float* m1w = (const float*)d_in[13]; const float* m1b = (const float*)d_in[14];
    const float* m2w = (const float*)d_in[15]; const float* m2b = (const float*)d_in[16];

    float* X0 = (float*)d_ws;
    float* X1 = X0 + (size_t)BN * 1024;
    float* T  = X1 + (size_t)BN * 1024;
    float* SQ = T  + (size_t)BN * 1024;
    int*   IDX = (int*)(SQ + BN);
    float* G  = (float*)(IDX + (size_t)BN * KK);
    unsigned short* XSh = (unsigned short*)(G + (size_t)BB * 1024);
    unsigned short* XSl = XSh + (size_t)BN * 512;   // max fin = 512
    unsigned short* WT  = XSl + (size_t)BN * 512;   // max 2*1024 x 2*512 bf16

    float* GP = T;   // gmax partials (T dead after last gathermax)

    const int fouts[5] = {64, 128, 256, 512, 1024};
    const int shifts[5] = {6, 7, 8, 9, 10};
    const float* cur = x0;
    int fin = 3;
    float* bufs[2] = {X0, X1};

    for (int l = 0; l < 5; ++l) {
        int fout = fouts[l];
        float* nxt = bufs[l & 1];
        int Fg = (l == 0) ? 32 : fin;      // padded K for MFMA path

        if (l == 0) {
            xsplit3_kernel<<<(BN + 255) / 256, 256, 0, stream>>>(cur, XSh, XSl, SQ);
        } else {
            xsplit_sq_kernel<<<BN / 4, 256, 0, stream>>>(cur, XSh, XSl, SQ, fin);
        }

        // d2 halves: D2a = T, D2b = nxt (both dead until gemm2 writes them)
        float* D2a = T;
        float* D2b = nxt;
        dim3 gg2(NN / 128, HC / 128, BB);
        knn_gram_kernel<<<gg2, 256, 0, stream>>>(XSh, XSl, SQ, D2a, Fg, 0);
        knn_gram_kernel<<<gg2, 256, 0, stream>>>(XSh, XSl, SQ, D2b, Fg, HC);
        knn_select_kernel<<<BN / 4, 256, 0, stream>>>(D2a, D2b, IDX);

        int nw = 2 * fout * Fg;
        wsplit_kernel<<<(nw + 255) / 256, 256, 0, stream>>>(w[l], WT, fin, Fg, fout);
        dim3 gg(BN / 128, (2 * fout) / 128);
        gemm2_mfma_kernel<<<gg, 256, 0, stream>>>(XSh, XSl, WT, bi[l], nxt, T, Fg, fout);

        gathermax_kernel<<<2048, 256, 0, stream>>>(nxt, T, IDX, nxt, shifts[l], BN * fout);

        cur = nxt;
        fin = fout;
    }

    dim3 x1(1024 / 256, BB, 16);
    gmax1_kernel<<<x1, 256, 0, stream>>>(cur, GP);
    dim3 x2(1024 / 256, BB);
    gmax2_kernel<<<x2, 256, 0, stream>>>(GP, G);

    mlp_kernel<<<BB, 128, 0, stream>>>(G, m0w, m0b, m1w, m1b, m2w, m2b, (float*)d_out);
}